// Round 4
// baseline (2431.163 us; speedup 1.0000x reference)
//
#include <hip/hip_runtime.h>
#include <cstdint>
#include <cstddef>

// DSDHLoss: faithful DCC loop on bitmask representation.
// B (+-1) -> 64-bit column masks + row-major bit-planes; Ybuf (0/1) -> masks.
// S=B B^T and R=B Y^T via popcount (exact integers == fp32 reference values).
// k2: A = (NT+lam) I + E (diag(S)=NT exactly). Solve X=A^-1 R by scalar-
//     preconditioned Neumann iteration (6 iters = fp32 fixed point).
// k3/l1: __launch_bounds__(256,2) -> 256-VGPR budget so p[64]/bf[64]/uc[64]
//     stay in registers (r3's VGPR=72 showed the compiler spilled them to
//     scratch under the default occupancy target).

#define NT 100000
#define WPR 1568      // padded u64 words per bit-row
#define NWREAL 1563   // ceil(100000/64)
#define NGRP 1563
#define ETA_MU 55.0f
#define LAM 0.1f

typedef unsigned long long u64;

__device__ inline u64 transpose64(u64 x, int lane) {
  const u64 ms[6] = {0x5555555555555555ull,0x3333333333333333ull,0x0F0F0F0F0F0F0F0Full,
                     0x00FF00FF00FF00FFull,0x0000FFFF0000FFFFull,0x00000000FFFFFFFFull};
#pragma unroll
  for (int si = 0; si < 6; ++si) {
    int s = 1 << si;
    u64 m = ms[si];
    u64 y = __shfl_xor(x, s, 64);
    if ((lane & s) == 0) x = (x & m) | ((y & m) << s);
    else                 x = (x & ~m) | ((y & ~m) >> s);
  }
  return x;
}

__device__ inline int wave_reduce_i32(int v) {
#pragma unroll
  for (int off = 32; off > 0; off >>= 1) v += __shfl_down(v, off, 64);
  return v;
}
__device__ inline double wave_reduce_f64(double v) {
#pragma unroll
  for (int off = 32; off > 0; off >>= 1) v += __shfl_down(v, off, 64);
  return v;
}

// column masks for B and Ybuf; owner[] = -1 everywhere (scatter fills later)
__global__ __launch_bounds__(256) void build_colmasks(
    const float* __restrict__ B, const float* __restrict__ Ybuf,
    u64* __restrict__ Bmask, u64* __restrict__ Ymask, int* __restrict__ owner) {
  int j = blockIdx.x * 256 + threadIdx.x;
  if (j >= NT) return;
  owner[j] = -1;
  u64 bm = 0;
#pragma unroll
  for (int i = 0; i < 64; ++i)
    bm |= ((u64)(B[(size_t)i * NT + j] > 0.0f)) << i;
  u64 m0 = 0, m1 = 0;
#pragma unroll
  for (int c = 0; c < 64; ++c)
    m0 |= ((u64)(Ybuf[(size_t)c * NT + j] > 0.5f)) << c;
#pragma unroll
  for (int c = 64; c < 100; ++c)
    m1 |= ((u64)(Ybuf[(size_t)c * NT + j] > 0.5f)) << (c - 64);
  Bmask[j] = bm;
  Ymask[2 * j] = m0;
  Ymask[2 * j + 1] = m1;
}

// scatter: Ybuf[:, ind[b]] = y[b]; owner[ind[b]] = b; batch y-masks; acc=0
__global__ void scatter_y(const float* __restrict__ y, const int* __restrict__ ind,
                          u64* __restrict__ Ymask, u64* __restrict__ ybatch,
                          int* __restrict__ owner, double* __restrict__ acc) {
  int b = threadIdx.x;
  if (b < 4) acc[b] = 0.0;
  if (b >= 128) return;
  u64 m0 = 0, m1 = 0;
  for (int c = 0; c < 100; ++c) {
    bool v = y[b * 100 + c] > 0.5f;
    if (c < 64) m0 |= ((u64)v) << c;
    else        m1 |= ((u64)v) << (c - 64);
  }
  ybatch[2 * b] = m0;
  ybatch[2 * b + 1] = m1;
  int col = ind[b];
  Ymask[2 * col] = m0;
  Ymask[2 * col + 1] = m1;
  owner[col] = b;
}

// column masks -> row-major bit planes (wave-level 64x64 bit transpose)
__global__ __launch_bounds__(256) void build_rows(
    const u64* __restrict__ Bmask, const u64* __restrict__ Ymask,
    u64* __restrict__ Brow, u64* __restrict__ Yrow) {
  int g = blockIdx.x * 4 + (threadIdx.x >> 6);
  int lane = threadIdx.x & 63;
  if (g >= NGRP) return;
  int j = g * 64 + lane;
  bool act = j < NT;
  u64 bm = act ? Bmask[j] : 0ull;
  u64 y0 = act ? Ymask[2 * j] : 0ull;
  u64 y1 = act ? Ymask[2 * j + 1] : 0ull;
  u64 tb = transpose64(bm, lane);
  Brow[(size_t)lane * WPR + g] = tb;
  u64 t0 = transpose64(y0, lane);
  Yrow[(size_t)lane * WPR + g] = t0;
  u64 t1 = transpose64(y1, lane);
  if (lane < 36) Yrow[(size_t)(64 + lane) * WPR + g] = t1;
}

// popcY: one block per class, parallel popc over the bit-row
__global__ __launch_bounds__(256) void popcY_k(const u64* __restrict__ Yrow,
                                               int* __restrict__ popcY) {
  int c = blockIdx.x;
  __shared__ int red[4];
  int s = 0;
  for (int w = threadIdx.x; w < NWREAL; w += 256)
    s += __popcll(Yrow[(size_t)c * WPR + w]);
  s = wave_reduce_i32(s);
  if ((threadIdx.x & 63) == 0) red[threadIdx.x >> 6] = s;
  __syncthreads();
  if (threadIdx.x == 0) popcY[c] = red[0] + red[1] + red[2] + red[3];
}

// K1: partial mismatch counts for S and AND-counts for R, per word-quarter
__global__ __launch_bounds__(256) void k1_sr(
    const u64* __restrict__ Brow, const u64* __restrict__ Yrow,
    int* __restrict__ S_part, int* __restrict__ R_part) {
  int k = blockIdx.x, q = blockIdx.y;
  __shared__ u64 sb[392];
  int w0 = q * 392;
  int nw = NWREAL - w0; if (nw > 392) nw = 392;
  for (int t = threadIdx.x; t < nw; t += 256) sb[t] = Brow[(size_t)k * WPR + w0 + t];
  __syncthreads();
  int wv = threadIdx.x >> 6, lane = threadIdx.x & 63;
  for (int l = wv; l < 64; l += 4) {
    const u64* br = Brow + (size_t)l * WPR + w0;
    int s = 0;
    for (int t = lane; t < nw; t += 64) s += __popcll(sb[t] ^ br[t]);
    s = wave_reduce_i32(s);
    if (lane == 0) S_part[q * 4096 + k * 64 + l] = s;
  }
  for (int c = wv; c < 100; c += 4) {
    const u64* yr = Yrow + (size_t)c * WPR + w0;
    int s = 0;
    for (int t = lane; t < nw; t += 64) s += __popcll(sb[t] & yr[t]);
    s = wave_reduce_i32(s);
    if (lane == 0) R_part[q * 6400 + k * 100 + c] = s;
  }
}

// K2: Neumann solve X = A^-1 R with A = (NT+LAM) I + E.
// X_{m+1} = alpha (R - E X_m), alpha = 1/(NT+LAM). 6 iterations.
// Epilogue: Wr/Wc stores + G = X X^T.
__global__ __launch_bounds__(256, 1) void k2_solve(
    const int* __restrict__ S_part, const int* __restrict__ R_part,
    const int* __restrict__ popcY, float* __restrict__ Wr,
    float* __restrict__ Wc, float* __restrict__ G) {
  __shared__ short sEi[64 * 64];   // [k][l] at k*64 + (l ^ (k&31)), values exact
  __shared__ float sXa[64 * 100];  // stride 100: b128 lane-vector reads conflict-free
  __shared__ float sXb[64 * 100];
  int tid = threadIdx.x;
  int wv = tid >> 6, k = tid & 63;
  const float alpha = 1.0f / (100000.0f + LAM);
  // E setup (exact int16; |E| ~ +-1500 for sign-of-normal rows)
  for (int e = tid; e < 4096; e += 256) {
    int kk = e >> 6, ll = e & 63;
    int mm = S_part[e] + S_part[4096 + e] + S_part[8192 + e] + S_part[12288 + e];
    int v = (kk == ll) ? 0 : (NT - 2 * mm);
    v = v > 32767 ? 32767 : (v < -32767 ? -32767 : v);
    sEi[kk * 64 + (ll ^ (kk & 31))] = (short)v;
  }
  // R into registers (wave chunks {28,24,24,24}, 16B-aligned), X0 = alpha*R
  int c0 = (wv == 0) ? 0 : (4 + wv * 24);   // 0,28,52,76
  int cq = (wv == 0) ? 7 : 6;               // quads per wave
  float4 rr4[7];
#pragma unroll
  for (int q = 0; q < 7; ++q) {
    if (q < cq) {
      float tmp[4];
#pragma unroll
      for (int e4 = 0; e4 < 4; ++e4) {
        int c = c0 + 4 * q + e4;
        int e = k * 100 + c;
        int rr = R_part[e] + R_part[6400 + e] + R_part[12800 + e] + R_part[19200 + e];
        tmp[e4] = (float)(2 * rr - popcY[c]);
      }
      rr4[q] = make_float4(tmp[0], tmp[1], tmp[2], tmp[3]);
      float4 x0 = make_float4(alpha * tmp[0], alpha * tmp[1], alpha * tmp[2], alpha * tmp[3]);
      *(float4*)&sXa[k * 100 + c0 + 4 * q] = x0;
    }
  }
  __syncthreads();
  float* Xs = sXa;
  float* Xd = sXb;
  for (int it = 0; it < 6; ++it) {
    float4 a4[7];
#pragma unroll
    for (int q = 0; q < 7; ++q)
      if (q < cq) a4[q] = rr4[q];
    for (int l = 0; l < 64; ++l) {
      float ev = (float)sEi[k * 64 + (l ^ (k & 31))];
      const float4* xr = (const float4*)&Xs[l * 100 + c0];   // broadcast b128
#pragma unroll
      for (int q = 0; q < 7; ++q) {
        if (q < cq) {
          float4 x4 = xr[q];
          a4[q].x -= ev * x4.x; a4[q].y -= ev * x4.y;
          a4[q].z -= ev * x4.z; a4[q].w -= ev * x4.w;
        }
      }
    }
#pragma unroll
    for (int q = 0; q < 7; ++q) {
      if (q < cq) {
        float4 o = make_float4(alpha * a4[q].x, alpha * a4[q].y,
                               alpha * a4[q].z, alpha * a4[q].w);
        *(float4*)&Xd[k * 100 + c0 + 4 * q] = o;
      }
    }
    __syncthreads();
    float* t = Xs; Xs = Xd; Xd = t;
  }
  // final X in sXa (6 swaps). Stores:
  for (int e = tid; e < 6400; e += 256) Wr[e] = sXa[e];   // identity layout
  for (int e = tid; e < 6400; e += 256) {
    int c = e >> 6, kk = e & 63;
    Wc[e] = sXa[kk * 100 + c];
  }
  // G = X X^T: lane k holds row k in regs; broadcast row i.
  float4 xl[25];
#pragma unroll
  for (int q = 0; q < 25; ++q) xl[q] = *(const float4*)&sXa[k * 100 + 4 * q];
  for (int ii = 0; ii < 16; ++ii) {
    int i = wv * 16 + ii;
    const float4* xi = (const float4*)&sXa[i * 100];
    float d0 = 0.f, d1 = 0.f, d2 = 0.f, d3 = 0.f;
#pragma unroll
    for (int q = 0; q < 25; ++q) {
      float4 b = xi[q];
      d0 += xl[q].x * b.x; d1 += xl[q].y * b.y;
      d2 += xl[q].z * b.z; d3 += xl[q].w * b.w;
    }
    G[i * 64 + k] = (d0 + d1) + (d2 + d3);
  }
}

// K3: per-column P = W@Ybuf_col (sparse over set classes) + 55*U_col, then
// exact sequential GS sign sweep reading G from GLOBAL with wave-uniform
// addresses (s_load path; no LDS for G). (256,2): 256-VGPR budget keeps
// p[64]+bf[64] register-resident (no scratch).
__global__ __launch_bounds__(256, 2) void k3_gs(
    const float* __restrict__ U, const float* __restrict__ u,
    const int* __restrict__ owner, const float* __restrict__ Wc,
    const float* __restrict__ Gm, u64* __restrict__ Bmask,
    u64* __restrict__ Brow, const u64* __restrict__ Ymask) {
  __shared__ float sW[100 * 68];   // [c][i], stride 68 (bank-spread for lane-varying c)
  for (int t = threadIdx.x; t < 6400; t += 256) {
    int c = t >> 6, i = t & 63;
    sW[c * 68 + i] = Wc[t];
  }
  __syncthreads();
  int g = blockIdx.x * 4 + (threadIdx.x >> 6);
  int lane = threadIdx.x & 63;
  if (g >= NGRP) return;
  int j = g * 64 + lane;
  bool act = j < NT;
  int jc = act ? j : NT - 1;
  int ow = owner[jc];
  float p[64];
  if (ow >= 0) {
#pragma unroll
    for (int i = 0; i < 64; ++i) p[i] = ETA_MU * u[ow * 64 + i];
  } else {
#pragma unroll
    for (int i = 0; i < 64; ++i) p[i] = ETA_MU * U[(size_t)i * NT + jc];
  }
  u64 y0 = Ymask[2 * jc], y1 = Ymask[2 * jc + 1];
  // sparse accumulation: identical fp32 result (skipped terms add exactly 0),
  // same ascending-c order as dense
  u64 mm = y0;
  while (mm) {
    int c = __builtin_ctzll(mm); mm &= mm - 1;
    const float4* wr = (const float4*)&sW[c * 68];
#pragma unroll
    for (int q = 0; q < 16; ++q) {
      float4 wvv = wr[q];
      p[4 * q + 0] += wvv.x; p[4 * q + 1] += wvv.y;
      p[4 * q + 2] += wvv.z; p[4 * q + 3] += wvv.w;
    }
  }
  mm = y1;
  while (mm) {
    int c = 64 + __builtin_ctzll(mm); mm &= mm - 1;
    const float4* wr = (const float4*)&sW[c * 68];
#pragma unroll
    for (int q = 0; q < 16; ++q) {
      float4 wvv = wr[q];
      p[4 * q + 0] += wvv.x; p[4 * q + 1] += wvv.y;
      p[4 * q + 2] += wvv.z; p[4 * q + 3] += wvv.w;
    }
  }
  u64 bm = Bmask[jc];
  float bf[64];
#pragma unroll
  for (int k = 0; k < 64; ++k) bf[k] = ((bm >> k) & 1ull) ? 1.0f : -1.0f;
#pragma unroll
  for (int i = 0; i < 64; ++i) {
    const float* gr = &Gm[i * 64];   // wave-uniform address -> scalar loads
    float d0 = 0.f, d1 = 0.f, d2 = 0.f, d3 = 0.f;
#pragma unroll
    for (int q = 0; q < 16; ++q) {
      d0 += gr[4 * q + 0] * bf[4 * q + 0];
      d1 += gr[4 * q + 1] * bf[4 * q + 1];
      d2 += gr[4 * q + 2] * bf[4 * q + 2];
      d3 += gr[4 * q + 3] * bf[4 * q + 3];
    }
    float val = p[i] - ((d0 + d1) + (d2 + d3)) + gr[i] * bf[i];
    bf[i] = (val > 0.0f) ? 1.0f : -1.0f;
  }
  u64 nm = 0;
#pragma unroll
  for (int k = 0; k < 64; ++k)
    if (bf[k] > 0.0f) nm |= 1ull << k;
  if (!act) nm = 0;
  if (act) Bmask[j] = nm;
  u64 tb = transpose64(nm, lane);
  Brow[(size_t)lane * WPR + g] = tb;
}

// L1: likelihood sum over 128 x 100000; u/ybatch read with wave-uniform
// addresses (scalar path), per-column U in VGPRs. (256,2): no uc[] spill.
__global__ __launch_bounds__(256, 2) void l1_like(
    const float* __restrict__ U, const float* __restrict__ u,
    const int* __restrict__ owner, const u64* __restrict__ Ymask,
    const u64* __restrict__ ybatch, double* __restrict__ acc) {
  int g = blockIdx.x * 4 + (threadIdx.x >> 6);
  int lane = threadIdx.x & 63;
  double lsum = 0.0;
  if (g < NGRP) {
    int j = g * 64 + lane;
    if (j < NT) {
      float uc[64];
      int ow = owner[j];
      if (ow >= 0) {
#pragma unroll
        for (int i = 0; i < 64; ++i) uc[i] = u[ow * 64 + i];
      } else {
#pragma unroll
        for (int i = 0; i < 64; ++i) uc[i] = U[(size_t)i * NT + j];
      }
      u64 y0 = Ymask[2 * j], y1 = Ymask[2 * j + 1];
      for (int b = 0; b < 128; ++b) {
        const float* ub = &u[b * 64];   // wave-uniform -> scalar loads
        float d0 = 0.f, d1 = 0.f, d2 = 0.f, d3 = 0.f;
#pragma unroll
        for (int q = 0; q < 16; ++q) {
          d0 += ub[4 * q + 0] * uc[4 * q + 0];
          d1 += ub[4 * q + 1] * uc[4 * q + 1];
          d2 += ub[4 * q + 2] * uc[4 * q + 2];
          d3 += ub[4 * q + 3] * uc[4 * q + 3];
        }
        float ip = 0.5f * ((d0 + d1) + (d2 + d3));
        bool s = ((ybatch[2 * b] & y0) | (ybatch[2 * b + 1] & y1)) != 0ull;
        float a = fabsf(ip);
        float like = __logf(1.0f + __expf(-a)) + fmaxf(ip, 0.0f) - (s ? ip : 0.0f);
        lsum += (double)like;
      }
    }
  }
  lsum = wave_reduce_f64(lsum);
  if (lane == 0) atomicAdd(&acc[0], lsum);
}

// L2 + finalize: cl_loss + reg_loss, then combine with acc[0] (l1 done).
__global__ __launch_bounds__(256) void l2_fin(
    const float* __restrict__ Wr, const float* __restrict__ y,
    const int* __restrict__ ind, const u64* __restrict__ Bmask,
    const double* __restrict__ acc, float* __restrict__ out) {
  __shared__ float sw[6400];   // W[i*100+c]
  __shared__ u64 sbm[128];
  __shared__ double dred[8];
  int tid = threadIdx.x;
  for (int t = tid; t < 6400; t += 256) sw[t] = Wr[t];
  if (tid < 128) sbm[tid] = Bmask[ind[tid]];
  __syncthreads();
  double cls = 0.0, regs = 0.0;
  for (int e = tid; e < 12800; e += 256) {
    int c = e >> 7, b = e & 127;
    u64 bm = sbm[b];
    float s = 0.0f;
#pragma unroll
    for (int i = 0; i < 64; ++i) {
      float w = sw[i * 100 + c];
      s += ((bm >> i) & 1ull) ? w : -w;
    }
    float d = y[b * 100 + c] - s;
    cls += (double)(d * d);
  }
  for (int e = tid; e < 6400; e += 256) {
    float w = sw[e];
    regs += (double)(w * w);
  }
  cls = wave_reduce_f64(cls);
  regs = wave_reduce_f64(regs);
  int wv = tid >> 6;
  if ((tid & 63) == 0) { dred[wv] = cls; dred[4 + wv] = regs; }
  __syncthreads();
  if (tid == 0) {
    double c = dred[0] + dred[1] + dred[2] + dred[3];
    double r = dred[4] + dred[5] + dred[6] + dred[7];
    out[0] = (float)(acc[0] * (1.0 / 12800000.0) + c * (1.0 / 12800.0) +
                     r * (0.1 / 6400.0));
  }
}

extern "C" void kernel_launch(void* const* d_in, const int* in_sizes, int n_in,
                              void* d_out, int out_size, void* d_ws, size_t ws_size,
                              hipStream_t stream) {
  const float* u    = (const float*)d_in[0];
  const float* y    = (const float*)d_in[1];
  const int*   ind  = (const int*)d_in[2];
  const float* U    = (const float*)d_in[3];
  const float* B    = (const float*)d_in[4];
  const float* Ybuf = (const float*)d_in[5];
  char* ws = (char*)d_ws;
  double* acc   = (double*)(ws + 0);
  u64* Bmask    = (u64*)(ws + 256);
  u64* Ymask    = (u64*)(ws + 800256);
  u64* Brow     = (u64*)(ws + 2400256);
  u64* Yrow     = (u64*)(ws + 3203072);
  u64* ybatch   = (u64*)(ws + 4457472);
  int* popcY    = (int*)(ws + 4459520);
  int* S_part   = (int*)(ws + 4460032);
  int* R_part   = (int*)(ws + 4525568);
  float* Wr     = (float*)(ws + 4627968);
  float* Wc     = (float*)(ws + 4653568);
  float* G      = (float*)(ws + 4679168);
  int* owner    = (int*)(ws + 4695552);

  build_colmasks<<<(NT + 255) / 256, 256, 0, stream>>>(B, Ybuf, Bmask, Ymask, owner);
  scatter_y<<<1, 128, 0, stream>>>(y, ind, Ymask, ybatch, owner, acc);
  build_rows<<<391, 256, 0, stream>>>(Bmask, Ymask, Brow, Yrow);
  popcY_k<<<100, 256, 0, stream>>>(Yrow, popcY);
  for (int it = 0; it < 10; ++it) {
    k1_sr<<<dim3(64, 4), 256, 0, stream>>>(Brow, Yrow, S_part, R_part);
    k2_solve<<<1, 256, 0, stream>>>(S_part, R_part, popcY, Wr, Wc, G);
    k3_gs<<<391, 256, 0, stream>>>(U, u, owner, Wc, G, Bmask, Brow, Ymask);
  }
  l1_like<<<391, 256, 0, stream>>>(U, u, owner, Ymask, ybatch, acc);
  l2_fin<<<1, 256, 0, stream>>>(Wr, y, ind, Bmask, acc, (float*)d_out);
}

// Round 5
// 1550.132 us; speedup vs baseline: 1.5684x; 1.5684x over previous
//
#include <hip/hip_runtime.h>
#include <cstdint>
#include <cstddef>

// DSDHLoss: faithful DCC loop on bitmask representation.
// B (+-1) -> 64-bit column masks + row-major bit-planes; Ybuf (0/1) -> masks.
// S=B B^T and R=B Y^T via popcount (exact integers == fp32 reference values).
// k1: bit-rows padded to 1568 zero words -> compile-time chunk (196 words,
//     Q=8, 512 blocks), row-k words in registers, unrolled batched loads,
//     level-synchronous shuffle reduce (41 independent chains).
// k2: Neumann solve (6 iters = fp32 fixed point of A^-1 R).
// k3: G staged in LDS -> GS recurrence reads are uniform broadcasts.

#define NT 100000
#define WPR 1568      // padded u64 words per bit-row (1563 real + 5 zero)
#define NWREAL 1563
#define NGRPP 1568    // padded group count
#define ETA_MU 55.0f
#define LAM 0.1f

typedef unsigned long long u64;

__device__ inline u64 transpose64(u64 x, int lane) {
  const u64 ms[6] = {0x5555555555555555ull,0x3333333333333333ull,0x0F0F0F0F0F0F0F0Full,
                     0x00FF00FF00FF00FFull,0x0000FFFF0000FFFFull,0x00000000FFFFFFFFull};
#pragma unroll
  for (int si = 0; si < 6; ++si) {
    int s = 1 << si;
    u64 m = ms[si];
    u64 y = __shfl_xor(x, s, 64);
    if ((lane & s) == 0) x = (x & m) | ((y & m) << s);
    else                 x = (x & ~m) | ((y & ~m) >> s);
  }
  return x;
}

__device__ inline int wave_reduce_i32(int v) {
#pragma unroll
  for (int off = 32; off > 0; off >>= 1) v += __shfl_down(v, off, 64);
  return v;
}
__device__ inline double wave_reduce_f64(double v) {
#pragma unroll
  for (int off = 32; off > 0; off >>= 1) v += __shfl_down(v, off, 64);
  return v;
}

// column masks for B and Ybuf; owner[] = -1 everywhere (scatter fills later)
__global__ __launch_bounds__(256) void build_colmasks(
    const float* __restrict__ B, const float* __restrict__ Ybuf,
    u64* __restrict__ Bmask, u64* __restrict__ Ymask,
    signed char* __restrict__ owner) {
  int j = blockIdx.x * 256 + threadIdx.x;
  if (j >= NT) return;
  owner[j] = -1;
  u64 bm = 0;
#pragma unroll
  for (int i = 0; i < 64; ++i)
    bm |= ((u64)(B[(size_t)i * NT + j] > 0.0f)) << i;
  u64 m0 = 0, m1 = 0;
#pragma unroll
  for (int c = 0; c < 64; ++c)
    m0 |= ((u64)(Ybuf[(size_t)c * NT + j] > 0.5f)) << c;
#pragma unroll
  for (int c = 64; c < 100; ++c)
    m1 |= ((u64)(Ybuf[(size_t)c * NT + j] > 0.5f)) << (c - 64);
  Bmask[j] = bm;
  Ymask[2 * j] = m0;
  Ymask[2 * j + 1] = m1;
}

// scatter: Ybuf[:, ind[b]] = y[b]; owner[ind[b]] = b; batch y-masks; acc=0
__global__ void scatter_y(const float* __restrict__ y, const int* __restrict__ ind,
                          u64* __restrict__ Ymask, u64* __restrict__ ybatch,
                          signed char* __restrict__ owner, double* __restrict__ acc) {
  int b = threadIdx.x;
  if (b < 4) acc[b] = 0.0;
  if (b >= 128) return;
  u64 m0 = 0, m1 = 0;
  for (int c = 0; c < 100; ++c) {
    bool v = y[b * 100 + c] > 0.5f;
    if (c < 64) m0 |= ((u64)v) << c;
    else        m1 |= ((u64)v) << (c - 64);
  }
  ybatch[2 * b] = m0;
  ybatch[2 * b + 1] = m1;
  int col = ind[b];
  Ymask[2 * col] = m0;
  Ymask[2 * col + 1] = m1;
  owner[col] = (signed char)b;
}

// column masks -> row-major bit planes; groups [1563,1568) write zeros (pad)
__global__ __launch_bounds__(256) void build_rows(
    const u64* __restrict__ Bmask, const u64* __restrict__ Ymask,
    u64* __restrict__ Brow, u64* __restrict__ Yrow) {
  int g = blockIdx.x * 4 + (threadIdx.x >> 6);
  int lane = threadIdx.x & 63;
  if (g >= NGRPP) return;
  int j = g * 64 + lane;
  bool act = j < NT;
  u64 bm = act ? Bmask[j] : 0ull;
  u64 y0 = act ? Ymask[2 * j] : 0ull;
  u64 y1 = act ? Ymask[2 * j + 1] : 0ull;
  u64 tb = transpose64(bm, lane);
  Brow[(size_t)lane * WPR + g] = tb;
  u64 t0 = transpose64(y0, lane);
  Yrow[(size_t)lane * WPR + g] = t0;
  u64 t1 = transpose64(y1, lane);
  if (lane < 36) Yrow[(size_t)(64 + lane) * WPR + g] = t1;
}

// popcY: one block per class
__global__ __launch_bounds__(256) void popcY_k(const u64* __restrict__ Yrow,
                                               int* __restrict__ popcY) {
  int c = blockIdx.x;
  __shared__ int red[4];
  int s = 0;
  for (int w = threadIdx.x; w < NWREAL; w += 256)
    s += __popcll(Yrow[(size_t)c * WPR + w]);
  s = wave_reduce_i32(s);
  if ((threadIdx.x & 63) == 0) red[threadIdx.x >> 6] = s;
  __syncthreads();
  if (threadIdx.x == 0) popcY[c] = red[0] + red[1] + red[2] + red[3];
}

// K1 v2: grid (64 k, 8 q). Chunk = 196 words (compile-time). Row-k words in
// registers; 16 S-rows + 25 R-rows per wave, batched unrolled loads,
// level-synchronous reduce.
__global__ __launch_bounds__(256, 4) void k1_sr(
    const u64* __restrict__ Brow, const u64* __restrict__ Yrow,
    int* __restrict__ S_part, int* __restrict__ R_part) {
  int k = blockIdx.x;
  int q = blockIdx.y;
  int w0 = q * 196;
  int wv = threadIdx.x >> 6, lane = threadIdx.x & 63;
  u64 tmask = (lane < 4) ? ~0ull : 0ull;
  const u64* bk = Brow + (size_t)k * WPR + w0;
  u64 b0 = bk[lane], b1 = bk[lane + 64], b2 = bk[lane + 128];
  u64 b3 = bk[192 + (lane & 3)] & tmask;
  int sS[16];
#pragma unroll
  for (int m = 0; m < 16; ++m) {
    const u64* br = Brow + (size_t)(4 * m + wv) * WPR + w0;
    u64 x0 = br[lane], x1 = br[lane + 64], x2 = br[lane + 128];
    u64 x3 = br[192 + (lane & 3)] & tmask;
    sS[m] = __popcll(x0 ^ b0) + __popcll(x1 ^ b1) +
            __popcll(x2 ^ b2) + __popcll(x3 ^ b3);
  }
  int sR[25];
#pragma unroll
  for (int m = 0; m < 25; ++m) {
    const u64* yr = Yrow + (size_t)(4 * m + wv) * WPR + w0;
    u64 x0 = yr[lane], x1 = yr[lane + 64], x2 = yr[lane + 128];
    u64 x3 = yr[192 + (lane & 3)] & tmask;
    sR[m] = __popcll(x0 & b0) + __popcll(x1 & b1) +
            __popcll(x2 & b2) + __popcll(x3 & b3);
  }
#pragma unroll
  for (int off = 32; off > 0; off >>= 1) {
#pragma unroll
    for (int m = 0; m < 16; ++m) sS[m] += __shfl_down(sS[m], off, 64);
#pragma unroll
    for (int m = 0; m < 25; ++m) sR[m] += __shfl_down(sR[m], off, 64);
  }
  if (lane == 0) {
#pragma unroll
    for (int m = 0; m < 16; ++m)
      S_part[q * 4096 + k * 64 + 4 * m + wv] = sS[m];
#pragma unroll
    for (int m = 0; m < 25; ++m)
      R_part[q * 6400 + k * 100 + 4 * m + wv] = sR[m];
  }
}

// K2: Neumann solve X = A^-1 R with A = (NT+LAM) I + E. 6 iterations.
__global__ __launch_bounds__(256, 1) void k2_solve(
    const int* __restrict__ S_part, const int* __restrict__ R_part,
    const int* __restrict__ popcY, float* __restrict__ Wr,
    float* __restrict__ Wc, float* __restrict__ G) {
  __shared__ short sEi[64 * 64];
  __shared__ float sXa[64 * 100];
  __shared__ float sXb[64 * 100];
  int tid = threadIdx.x;
  int wv = tid >> 6, k = tid & 63;
  const float alpha = 1.0f / (100000.0f + LAM);
  for (int e = tid; e < 4096; e += 256) {
    int kk = e >> 6, ll = e & 63;
    int mm = 0;
#pragma unroll
    for (int qq = 0; qq < 8; ++qq) mm += S_part[qq * 4096 + e];
    int v = (kk == ll) ? 0 : (NT - 2 * mm);
    v = v > 32767 ? 32767 : (v < -32767 ? -32767 : v);
    sEi[kk * 64 + (ll ^ (kk & 31))] = (short)v;
  }
  int c0 = (wv == 0) ? 0 : (4 + wv * 24);
  int cq = (wv == 0) ? 7 : 6;
  float4 rr4[7];
#pragma unroll
  for (int q = 0; q < 7; ++q) {
    if (q < cq) {
      float tmp[4];
#pragma unroll
      for (int e4 = 0; e4 < 4; ++e4) {
        int c = c0 + 4 * q + e4;
        int e = k * 100 + c;
        int rr = 0;
#pragma unroll
        for (int qq = 0; qq < 8; ++qq) rr += R_part[qq * 6400 + e];
        tmp[e4] = (float)(2 * rr - popcY[c]);
      }
      rr4[q] = make_float4(tmp[0], tmp[1], tmp[2], tmp[3]);
      float4 x0 = make_float4(alpha * tmp[0], alpha * tmp[1], alpha * tmp[2], alpha * tmp[3]);
      *(float4*)&sXa[k * 100 + c0 + 4 * q] = x0;
    }
  }
  __syncthreads();
  float* Xs = sXa;
  float* Xd = sXb;
  for (int it = 0; it < 6; ++it) {
    float4 a4[7];
#pragma unroll
    for (int q = 0; q < 7; ++q)
      if (q < cq) a4[q] = rr4[q];
    for (int l = 0; l < 64; ++l) {
      float ev = (float)sEi[k * 64 + (l ^ (k & 31))];
      const float4* xr = (const float4*)&Xs[l * 100 + c0];
#pragma unroll
      for (int q = 0; q < 7; ++q) {
        if (q < cq) {
          float4 x4 = xr[q];
          a4[q].x -= ev * x4.x; a4[q].y -= ev * x4.y;
          a4[q].z -= ev * x4.z; a4[q].w -= ev * x4.w;
        }
      }
    }
#pragma unroll
    for (int q = 0; q < 7; ++q) {
      if (q < cq) {
        float4 o = make_float4(alpha * a4[q].x, alpha * a4[q].y,
                               alpha * a4[q].z, alpha * a4[q].w);
        *(float4*)&Xd[k * 100 + c0 + 4 * q] = o;
      }
    }
    __syncthreads();
    float* t = Xs; Xs = Xd; Xd = t;
  }
  for (int e = tid; e < 6400; e += 256) Wr[e] = sXa[e];
  for (int e = tid; e < 6400; e += 256) {
    int c = e >> 6, kk = e & 63;
    Wc[e] = sXa[kk * 100 + c];
  }
  float4 xl[25];
#pragma unroll
  for (int q = 0; q < 25; ++q) xl[q] = *(const float4*)&sXa[k * 100 + 4 * q];
  for (int ii = 0; ii < 16; ++ii) {
    int i = wv * 16 + ii;
    const float4* xi = (const float4*)&sXa[i * 100];
    float d0 = 0.f, d1 = 0.f, d2 = 0.f, d3 = 0.f;
#pragma unroll
    for (int q = 0; q < 25; ++q) {
      float4 b = xi[q];
      d0 += xl[q].x * b.x; d1 += xl[q].y * b.y;
      d2 += xl[q].z * b.z; d3 += xl[q].w * b.w;
    }
    G[i * 64 + k] = (d0 + d1) + (d2 + d3);
  }
}

// K3: P = W@Ybuf_col (sparse) + 55*U_col, then exact sequential GS sweep.
// G staged in LDS: GS recurrence reads are uniform-address broadcasts.
__global__ __launch_bounds__(256, 2) void k3_gs(
    const float* __restrict__ U, const float* __restrict__ u,
    const signed char* __restrict__ owner, const float* __restrict__ Wc,
    const float* __restrict__ Gm, u64* __restrict__ Bmask,
    u64* __restrict__ Brow, const u64* __restrict__ Ymask) {
  __shared__ float sW[100 * 68];   // [c][i]
  __shared__ float sG[4096];       // [i][k]
  for (int t = threadIdx.x; t < 6400; t += 256) {
    int c = t >> 6, i = t & 63;
    sW[c * 68 + i] = Wc[t];
  }
  for (int t = threadIdx.x; t < 4096; t += 256) sG[t] = Gm[t];
  __syncthreads();
  int g = blockIdx.x * 4 + (threadIdx.x >> 6);   // grid 392 -> g < 1568
  int lane = threadIdx.x & 63;
  int j = g * 64 + lane;
  bool act = j < NT;
  int jc = act ? j : NT - 1;
  int ow = owner[jc];
  float p[64];
  if (ow >= 0) {
#pragma unroll
    for (int i = 0; i < 64; ++i) p[i] = ETA_MU * u[ow * 64 + i];
  } else {
#pragma unroll
    for (int i = 0; i < 64; ++i) p[i] = ETA_MU * U[(size_t)i * NT + jc];
  }
  u64 y0 = Ymask[2 * jc], y1 = Ymask[2 * jc + 1];
  u64 mm = y0;
  while (mm) {
    int c = __builtin_ctzll(mm); mm &= mm - 1;
    const float4* wr = (const float4*)&sW[c * 68];
#pragma unroll
    for (int q = 0; q < 16; ++q) {
      float4 wvv = wr[q];
      p[4 * q + 0] += wvv.x; p[4 * q + 1] += wvv.y;
      p[4 * q + 2] += wvv.z; p[4 * q + 3] += wvv.w;
    }
  }
  mm = y1;
  while (mm) {
    int c = 64 + __builtin_ctzll(mm); mm &= mm - 1;
    const float4* wr = (const float4*)&sW[c * 68];
#pragma unroll
    for (int q = 0; q < 16; ++q) {
      float4 wvv = wr[q];
      p[4 * q + 0] += wvv.x; p[4 * q + 1] += wvv.y;
      p[4 * q + 2] += wvv.z; p[4 * q + 3] += wvv.w;
    }
  }
  u64 bm = Bmask[jc];
  float bf[64];
#pragma unroll
  for (int k = 0; k < 64; ++k) bf[k] = ((bm >> k) & 1ull) ? 1.0f : -1.0f;
#pragma unroll
  for (int i = 0; i < 64; ++i) {
    const float4* gr = (const float4*)&sG[i * 64];   // uniform broadcast
    float d0 = 0.f, d1 = 0.f, d2 = 0.f, d3 = 0.f;
#pragma unroll
    for (int q = 0; q < 16; ++q) {
      float4 gv = gr[q];
      d0 += gv.x * bf[4 * q + 0];
      d1 += gv.y * bf[4 * q + 1];
      d2 += gv.z * bf[4 * q + 2];
      d3 += gv.w * bf[4 * q + 3];
    }
    float val = p[i] - ((d0 + d1) + (d2 + d3)) + sG[i * 64 + i] * bf[i];
    bf[i] = (val > 0.0f) ? 1.0f : -1.0f;
  }
  u64 nm = 0;
#pragma unroll
  for (int k = 0; k < 64; ++k)
    if (bf[k] > 0.0f) nm |= 1ull << k;
  if (!act) nm = 0;
  if (act) Bmask[j] = nm;
  u64 tb = transpose64(nm, lane);
  Brow[(size_t)lane * WPR + g] = tb;
}

// L1: likelihood sum; u/ybatch staged in LDS (uniform broadcast in b-loop).
__global__ __launch_bounds__(256, 2) void l1_like(
    const float* __restrict__ U, const float* __restrict__ u,
    const signed char* __restrict__ owner, const u64* __restrict__ Ymask,
    const u64* __restrict__ ybatch, double* __restrict__ acc) {
  __shared__ float su[8192];
  __shared__ u64 sy[256];
  for (int t = threadIdx.x; t < 8192; t += 256) su[t] = u[t];
  if (threadIdx.x < 256) sy[threadIdx.x] = ybatch[threadIdx.x];
  __syncthreads();
  int g = blockIdx.x * 4 + (threadIdx.x >> 6);
  int lane = threadIdx.x & 63;
  double lsum = 0.0;
  if (g < 1563) {
    int j = g * 64 + lane;
    if (j < NT) {
      float uc[64];
      int ow = owner[j];
      if (ow >= 0) {
#pragma unroll
        for (int i = 0; i < 64; ++i) uc[i] = su[ow * 64 + i];
      } else {
#pragma unroll
        for (int i = 0; i < 64; ++i) uc[i] = U[(size_t)i * NT + j];
      }
      u64 y0 = Ymask[2 * j], y1 = Ymask[2 * j + 1];
      for (int b = 0; b < 128; ++b) {
        const float4* ub = (const float4*)&su[b * 64];
        float d0 = 0.f, d1 = 0.f, d2 = 0.f, d3 = 0.f;
#pragma unroll
        for (int q = 0; q < 16; ++q) {
          float4 uv = ub[q];
          d0 += uv.x * uc[4 * q + 0];
          d1 += uv.y * uc[4 * q + 1];
          d2 += uv.z * uc[4 * q + 2];
          d3 += uv.w * uc[4 * q + 3];
        }
        float ip = 0.5f * ((d0 + d1) + (d2 + d3));
        bool s = ((sy[2 * b] & y0) | (sy[2 * b + 1] & y1)) != 0ull;
        float a = fabsf(ip);
        float like = __logf(1.0f + __expf(-a)) + fmaxf(ip, 0.0f) - (s ? ip : 0.0f);
        lsum += (double)like;
      }
    }
  }
  lsum = wave_reduce_f64(lsum);
  if (lane == 0) atomicAdd(&acc[0], lsum);
}

// L2 + finalize
__global__ __launch_bounds__(256) void l2_fin(
    const float* __restrict__ Wr, const float* __restrict__ y,
    const int* __restrict__ ind, const u64* __restrict__ Bmask,
    const double* __restrict__ acc, float* __restrict__ out) {
  __shared__ float sw[6400];
  __shared__ u64 sbm[128];
  __shared__ double dred[8];
  int tid = threadIdx.x;
  for (int t = tid; t < 6400; t += 256) sw[t] = Wr[t];
  if (tid < 128) sbm[tid] = Bmask[ind[tid]];
  __syncthreads();
  double cls = 0.0, regs = 0.0;
  for (int e = tid; e < 12800; e += 256) {
    int c = e >> 7, b = e & 127;
    u64 bm = sbm[b];
    float s = 0.0f;
#pragma unroll
    for (int i = 0; i < 64; ++i) {
      float w = sw[i * 100 + c];
      s += ((bm >> i) & 1ull) ? w : -w;
    }
    float d = y[b * 100 + c] - s;
    cls += (double)(d * d);
  }
  for (int e = tid; e < 6400; e += 256) {
    float w = sw[e];
    regs += (double)(w * w);
  }
  cls = wave_reduce_f64(cls);
  regs = wave_reduce_f64(regs);
  int wv = tid >> 6;
  if ((tid & 63) == 0) { dred[wv] = cls; dred[4 + wv] = regs; }
  __syncthreads();
  if (tid == 0) {
    double c = dred[0] + dred[1] + dred[2] + dred[3];
    double r = dred[4] + dred[5] + dred[6] + dred[7];
    out[0] = (float)(acc[0] * (1.0 / 12800000.0) + c * (1.0 / 12800.0) +
                     r * (0.1 / 6400.0));
  }
}

extern "C" void kernel_launch(void* const* d_in, const int* in_sizes, int n_in,
                              void* d_out, int out_size, void* d_ws, size_t ws_size,
                              hipStream_t stream) {
  const float* u    = (const float*)d_in[0];
  const float* y    = (const float*)d_in[1];
  const int*   ind  = (const int*)d_in[2];
  const float* U    = (const float*)d_in[3];
  const float* B    = (const float*)d_in[4];
  const float* Ybuf = (const float*)d_in[5];
  char* ws = (char*)d_ws;
  double* acc        = (double*)(ws + 0);
  u64* Bmask         = (u64*)(ws + 256);
  u64* Ymask         = (u64*)(ws + 800256);
  u64* Brow          = (u64*)(ws + 2400256);
  u64* Yrow          = (u64*)(ws + 3203072);
  u64* ybatch        = (u64*)(ws + 4457472);
  int* popcY         = (int*)(ws + 4459520);
  int* S_part        = (int*)(ws + 4460032);   // 8*4096 ints
  int* R_part        = (int*)(ws + 4591104);   // 8*6400 ints
  float* Wr          = (float*)(ws + 4795904);
  float* Wc          = (float*)(ws + 4821504);
  float* G           = (float*)(ws + 4847104);
  signed char* owner = (signed char*)(ws + 4863488);

  build_colmasks<<<(NT + 255) / 256, 256, 0, stream>>>(B, Ybuf, Bmask, Ymask, owner);
  scatter_y<<<1, 128, 0, stream>>>(y, ind, Ymask, ybatch, owner, acc);
  build_rows<<<392, 256, 0, stream>>>(Bmask, Ymask, Brow, Yrow);
  popcY_k<<<100, 256, 0, stream>>>(Yrow, popcY);
  for (int it = 0; it < 10; ++it) {
    k1_sr<<<dim3(64, 8), 256, 0, stream>>>(Brow, Yrow, S_part, R_part);
    k2_solve<<<1, 256, 0, stream>>>(S_part, R_part, popcY, Wr, Wc, G);
    k3_gs<<<392, 256, 0, stream>>>(U, u, owner, Wc, G, Bmask, Brow, Ymask);
  }
  l1_like<<<391, 256, 0, stream>>>(U, u, owner, Ymask, ybatch, acc);
  l2_fin<<<1, 256, 0, stream>>>(Wr, y, ind, Bmask, acc, (float*)d_out);
}

// Round 6
// 1521.640 us; speedup vs baseline: 1.5977x; 1.0187x over previous
//
#include <hip/hip_runtime.h>
#include <cstdint>
#include <cstddef>

// DSDHLoss: faithful DCC loop on bitmask representation.
// B (+-1) -> 64-bit column masks + row-major bit-planes; Ybuf (0/1) -> masks.
// S=B B^T and R=B Y^T via popcount (exact integers == fp32 reference values).
// k1: padded bit-rows, compile-time chunks, register popcounts.
// k2a: Neumann solve (6 iters), columns split over 4 blocks (independent).
// k2b: G = W W^T, 4 blocks x 16 rows.
// k3/l1: G and u staged in LDS as fp16 (halves broadcast-read issue).

#define NT 100000
#define WPR 1568      // padded u64 words per bit-row (1563 real + 5 zero)
#define NWREAL 1563
#define NGRPP 1568    // padded group count
#define ETA_MU 55.0f
#define LAM 0.1f

typedef unsigned long long u64;
typedef _Float16 half8 __attribute__((ext_vector_type(8)));

__device__ inline u64 transpose64(u64 x, int lane) {
  const u64 ms[6] = {0x5555555555555555ull,0x3333333333333333ull,0x0F0F0F0F0F0F0F0Full,
                     0x00FF00FF00FF00FFull,0x0000FFFF0000FFFFull,0x00000000FFFFFFFFull};
#pragma unroll
  for (int si = 0; si < 6; ++si) {
    int s = 1 << si;
    u64 m = ms[si];
    u64 y = __shfl_xor(x, s, 64);
    if ((lane & s) == 0) x = (x & m) | ((y & m) << s);
    else                 x = (x & ~m) | ((y & ~m) >> s);
  }
  return x;
}

__device__ inline int wave_reduce_i32(int v) {
#pragma unroll
  for (int off = 32; off > 0; off >>= 1) v += __shfl_down(v, off, 64);
  return v;
}
__device__ inline double wave_reduce_f64(double v) {
#pragma unroll
  for (int off = 32; off > 0; off >>= 1) v += __shfl_down(v, off, 64);
  return v;
}

// column masks for B and Ybuf; owner[] = -1 everywhere (scatter fills later)
__global__ __launch_bounds__(256) void build_colmasks(
    const float* __restrict__ B, const float* __restrict__ Ybuf,
    u64* __restrict__ Bmask, u64* __restrict__ Ymask,
    signed char* __restrict__ owner) {
  int j = blockIdx.x * 256 + threadIdx.x;
  if (j >= NT) return;
  owner[j] = -1;
  u64 bm = 0;
#pragma unroll
  for (int i = 0; i < 64; ++i)
    bm |= ((u64)(B[(size_t)i * NT + j] > 0.0f)) << i;
  u64 m0 = 0, m1 = 0;
#pragma unroll
  for (int c = 0; c < 64; ++c)
    m0 |= ((u64)(Ybuf[(size_t)c * NT + j] > 0.5f)) << c;
#pragma unroll
  for (int c = 64; c < 100; ++c)
    m1 |= ((u64)(Ybuf[(size_t)c * NT + j] > 0.5f)) << (c - 64);
  Bmask[j] = bm;
  Ymask[2 * j] = m0;
  Ymask[2 * j + 1] = m1;
}

// scatter: Ybuf[:, ind[b]] = y[b]; owner[ind[b]] = b; batch y-masks; acc=0
__global__ void scatter_y(const float* __restrict__ y, const int* __restrict__ ind,
                          u64* __restrict__ Ymask, u64* __restrict__ ybatch,
                          signed char* __restrict__ owner, double* __restrict__ acc) {
  int b = threadIdx.x;
  if (b < 4) acc[b] = 0.0;
  if (b >= 128) return;
  u64 m0 = 0, m1 = 0;
  for (int c = 0; c < 100; ++c) {
    bool v = y[b * 100 + c] > 0.5f;
    if (c < 64) m0 |= ((u64)v) << c;
    else        m1 |= ((u64)v) << (c - 64);
  }
  ybatch[2 * b] = m0;
  ybatch[2 * b + 1] = m1;
  int col = ind[b];
  Ymask[2 * col] = m0;
  Ymask[2 * col + 1] = m1;
  owner[col] = (signed char)b;
}

// column masks -> row-major bit planes; groups [1563,1568) write zeros (pad)
__global__ __launch_bounds__(256) void build_rows(
    const u64* __restrict__ Bmask, const u64* __restrict__ Ymask,
    u64* __restrict__ Brow, u64* __restrict__ Yrow) {
  int g = blockIdx.x * 4 + (threadIdx.x >> 6);
  int lane = threadIdx.x & 63;
  if (g >= NGRPP) return;
  int j = g * 64 + lane;
  bool act = j < NT;
  u64 bm = act ? Bmask[j] : 0ull;
  u64 y0 = act ? Ymask[2 * j] : 0ull;
  u64 y1 = act ? Ymask[2 * j + 1] : 0ull;
  u64 tb = transpose64(bm, lane);
  Brow[(size_t)lane * WPR + g] = tb;
  u64 t0 = transpose64(y0, lane);
  Yrow[(size_t)lane * WPR + g] = t0;
  u64 t1 = transpose64(y1, lane);
  if (lane < 36) Yrow[(size_t)(64 + lane) * WPR + g] = t1;
}

// popcY: one block per class
__global__ __launch_bounds__(256) void popcY_k(const u64* __restrict__ Yrow,
                                               int* __restrict__ popcY) {
  int c = blockIdx.x;
  __shared__ int red[4];
  int s = 0;
  for (int w = threadIdx.x; w < NWREAL; w += 256)
    s += __popcll(Yrow[(size_t)c * WPR + w]);
  s = wave_reduce_i32(s);
  if ((threadIdx.x & 63) == 0) red[threadIdx.x >> 6] = s;
  __syncthreads();
  if (threadIdx.x == 0) popcY[c] = red[0] + red[1] + red[2] + red[3];
}

// K1: grid (64 k, 8 q). Chunk = 196 words (compile-time). Register popcounts.
__global__ __launch_bounds__(256, 4) void k1_sr(
    const u64* __restrict__ Brow, const u64* __restrict__ Yrow,
    int* __restrict__ S_part, int* __restrict__ R_part) {
  int k = blockIdx.x;
  int q = blockIdx.y;
  int w0 = q * 196;
  int wv = threadIdx.x >> 6, lane = threadIdx.x & 63;
  u64 tmask = (lane < 4) ? ~0ull : 0ull;
  const u64* bk = Brow + (size_t)k * WPR + w0;
  u64 b0 = bk[lane], b1 = bk[lane + 64], b2 = bk[lane + 128];
  u64 b3 = bk[192 + (lane & 3)] & tmask;
  int sS[16];
#pragma unroll
  for (int m = 0; m < 16; ++m) {
    const u64* br = Brow + (size_t)(4 * m + wv) * WPR + w0;
    u64 x0 = br[lane], x1 = br[lane + 64], x2 = br[lane + 128];
    u64 x3 = br[192 + (lane & 3)] & tmask;
    sS[m] = __popcll(x0 ^ b0) + __popcll(x1 ^ b1) +
            __popcll(x2 ^ b2) + __popcll(x3 ^ b3);
  }
  int sR[25];
#pragma unroll
  for (int m = 0; m < 25; ++m) {
    const u64* yr = Yrow + (size_t)(4 * m + wv) * WPR + w0;
    u64 x0 = yr[lane], x1 = yr[lane + 64], x2 = yr[lane + 128];
    u64 x3 = yr[192 + (lane & 3)] & tmask;
    sR[m] = __popcll(x0 & b0) + __popcll(x1 & b1) +
            __popcll(x2 & b2) + __popcll(x3 & b3);
  }
#pragma unroll
  for (int off = 32; off > 0; off >>= 1) {
#pragma unroll
    for (int m = 0; m < 16; ++m) sS[m] += __shfl_down(sS[m], off, 64);
#pragma unroll
    for (int m = 0; m < 25; ++m) sR[m] += __shfl_down(sR[m], off, 64);
  }
  if (lane == 0) {
#pragma unroll
    for (int m = 0; m < 16; ++m)
      S_part[q * 4096 + k * 64 + 4 * m + wv] = sS[m];
#pragma unroll
    for (int m = 0; m < 25; ++m)
      R_part[q * 6400 + k * 100 + 4 * m + wv] = sR[m];
  }
}

// K2a: Neumann solve X = A^-1 R, columns split across 4 blocks (independent).
// Block b handles quads [qbase, qbase+Q) of the 26-quad (104 padded cols) range.
__global__ __launch_bounds__(256, 1) void k2a_solve(
    const int* __restrict__ S_part, const int* __restrict__ R_part,
    const int* __restrict__ popcY, float* __restrict__ Wr,
    float* __restrict__ Wc) {
  __shared__ short sEi[4096];      // [k][l^ (k&31)] exact i16
  __shared__ float sXa[64 * 28];   // [k][local col], stride 28
  __shared__ float sXb[64 * 28];
  int tid = threadIdx.x;
  int wv = tid >> 6, k = tid & 63;
  int b = blockIdx.x;
  const int qbase_t[4] = {0, 7, 14, 20};
  const int qcnt_t[4]  = {7, 7, 6, 6};
  int qbase = qbase_t[b], Q = qcnt_t[b];
  const int off7[4] = {0, 2, 4, 6}, cnt7[4] = {2, 2, 2, 1};
  const int off6[4] = {0, 2, 4, 5}, cnt6[4] = {2, 2, 1, 1};
  int woff = (Q == 7) ? off7[wv] : off6[wv];
  int wcnt = (Q == 7) ? cnt7[wv] : cnt6[wv];
  const float alpha = 1.0f / (100000.0f + LAM);
  for (int e = tid; e < 4096; e += 256) {
    int kk = e >> 6, ll = e & 63;
    int mm = 0;
#pragma unroll
    for (int qq = 0; qq < 8; ++qq) mm += S_part[qq * 4096 + e];
    int v = (kk == ll) ? 0 : (NT - 2 * mm);
    v = v > 32767 ? 32767 : (v < -32767 ? -32767 : v);
    sEi[kk * 64 + (ll ^ (kk & 31))] = (short)v;
  }
  float4 rr4[2];
#pragma unroll
  for (int q = 0; q < 2; ++q) {
    if (q < wcnt) {
      float tmp[4];
#pragma unroll
      for (int e4 = 0; e4 < 4; ++e4) {
        int cg = 4 * (qbase + woff + q) + e4;
        float rv = 0.0f;
        if (cg < 100) {
          int rr = 0;
#pragma unroll
          for (int qq = 0; qq < 8; ++qq) rr += R_part[qq * 6400 + k * 100 + cg];
          rv = (float)(2 * rr - popcY[cg]);
        }
        tmp[e4] = rv;
      }
      rr4[q] = make_float4(tmp[0], tmp[1], tmp[2], tmp[3]);
      float4 x0 = make_float4(alpha * tmp[0], alpha * tmp[1],
                              alpha * tmp[2], alpha * tmp[3]);
      *(float4*)&sXa[k * 28 + 4 * (woff + q)] = x0;
    }
  }
  __syncthreads();
  float* Xs = sXa;
  float* Xd = sXb;
  for (int it = 0; it < 6; ++it) {
    float4 a4[2];
#pragma unroll
    for (int q = 0; q < 2; ++q)
      if (q < wcnt) a4[q] = rr4[q];
    for (int l = 0; l < 64; ++l) {
      float ev = (float)sEi[k * 64 + (l ^ (k & 31))];
      const float4* xr = (const float4*)&Xs[l * 28 + 4 * woff];
#pragma unroll
      for (int q = 0; q < 2; ++q) {
        if (q < wcnt) {
          float4 x4 = xr[q];
          a4[q].x -= ev * x4.x; a4[q].y -= ev * x4.y;
          a4[q].z -= ev * x4.z; a4[q].w -= ev * x4.w;
        }
      }
    }
#pragma unroll
    for (int q = 0; q < 2; ++q) {
      if (q < wcnt) {
        float4 o = make_float4(alpha * a4[q].x, alpha * a4[q].y,
                               alpha * a4[q].z, alpha * a4[q].w);
        *(float4*)&Xd[k * 28 + 4 * (woff + q)] = o;
      }
    }
    __syncthreads();
    float* t = Xs; Xs = Xd; Xd = t;
  }
  // final X in sXa (6 swaps)
#pragma unroll
  for (int q = 0; q < 2; ++q) {
    if (q < wcnt) {
#pragma unroll
      for (int e4 = 0; e4 < 4; ++e4) {
        int cg = 4 * (qbase + woff + q) + e4;
        if (cg < 100) {
          float v = sXa[k * 28 + 4 * (woff + q) + e4];
          Wr[k * 100 + cg] = v;
          Wc[cg * 64 + k] = v;
        }
      }
    }
  }
}

// K2b: G = W W^T, 4 blocks x 16 rows each.
__global__ __launch_bounds__(256, 1) void k2b_gram(
    const float* __restrict__ Wr, float* __restrict__ G) {
  __shared__ float sX[6400];
  int tid = threadIdx.x, wv = tid >> 6, k = tid & 63;
  for (int t = tid; t < 6400; t += 256) sX[t] = Wr[t];
  __syncthreads();
  float4 xl[25];
#pragma unroll
  for (int q = 0; q < 25; ++q) xl[q] = *(const float4*)&sX[k * 100 + 4 * q];
#pragma unroll
  for (int ii = 0; ii < 4; ++ii) {
    int i = blockIdx.x * 16 + wv * 4 + ii;
    const float4* xi = (const float4*)&sX[i * 100];
    float d0 = 0.f, d1 = 0.f, d2 = 0.f, d3 = 0.f;
#pragma unroll
    for (int q = 0; q < 25; ++q) {
      float4 a = xi[q];
      d0 += xl[q].x * a.x; d1 += xl[q].y * a.y;
      d2 += xl[q].z * a.z; d3 += xl[q].w * a.w;
    }
    G[i * 64 + k] = (d0 + d1) + (d2 + d3);
  }
}

// K3: P = W@Ybuf_col (sparse) + 55*U_col, then exact sequential GS sweep.
// G in LDS as fp16 (8 broadcast b128 per row instead of 16).
__global__ __launch_bounds__(256, 2) void k3_gs(
    const float* __restrict__ U, const float* __restrict__ u,
    const signed char* __restrict__ owner, const float* __restrict__ Wc,
    const float* __restrict__ Gm, u64* __restrict__ Bmask,
    u64* __restrict__ Brow, const u64* __restrict__ Ymask) {
  __shared__ float sW[100 * 68];     // [c][i] fp32 (gathered rows)
  __shared__ _Float16 sGh[64 * 64];  // [i][k] fp16 (broadcast rows)
  for (int t = threadIdx.x; t < 6400; t += 256) {
    int c = t >> 6, i = t & 63;
    sW[c * 68 + i] = Wc[t];
  }
  for (int t = threadIdx.x; t < 4096; t += 256) sGh[t] = (_Float16)Gm[t];
  __syncthreads();
  int g = blockIdx.x * 4 + (threadIdx.x >> 6);   // grid 392 -> g < 1568
  int lane = threadIdx.x & 63;
  int j = g * 64 + lane;
  bool act = j < NT;
  int jc = act ? j : NT - 1;
  int ow = owner[jc];
  float p[64];
  if (ow >= 0) {
#pragma unroll
    for (int i = 0; i < 64; ++i) p[i] = ETA_MU * u[ow * 64 + i];
  } else {
#pragma unroll
    for (int i = 0; i < 64; ++i) p[i] = ETA_MU * U[(size_t)i * NT + jc];
  }
  u64 y0 = Ymask[2 * jc], y1 = Ymask[2 * jc + 1];
  u64 mm = y0;
  while (mm) {
    int c = __builtin_ctzll(mm); mm &= mm - 1;
    const float4* wr = (const float4*)&sW[c * 68];
#pragma unroll
    for (int q = 0; q < 16; ++q) {
      float4 wvv = wr[q];
      p[4 * q + 0] += wvv.x; p[4 * q + 1] += wvv.y;
      p[4 * q + 2] += wvv.z; p[4 * q + 3] += wvv.w;
    }
  }
  mm = y1;
  while (mm) {
    int c = 64 + __builtin_ctzll(mm); mm &= mm - 1;
    const float4* wr = (const float4*)&sW[c * 68];
#pragma unroll
    for (int q = 0; q < 16; ++q) {
      float4 wvv = wr[q];
      p[4 * q + 0] += wvv.x; p[4 * q + 1] += wvv.y;
      p[4 * q + 2] += wvv.z; p[4 * q + 3] += wvv.w;
    }
  }
  u64 bm = Bmask[jc];
  float bf[64];
#pragma unroll
  for (int k = 0; k < 64; ++k) bf[k] = ((bm >> k) & 1ull) ? 1.0f : -1.0f;
#pragma unroll
  for (int i = 0; i < 64; ++i) {
    const half8* gr = (const half8*)&sGh[i * 64];   // uniform broadcast
    float d0 = 0.f, d1 = 0.f, d2 = 0.f, d3 = 0.f;
#pragma unroll
    for (int q = 0; q < 8; ++q) {
      half8 gv = gr[q];
      d0 += (float)gv[0] * bf[8 * q + 0];
      d1 += (float)gv[1] * bf[8 * q + 1];
      d2 += (float)gv[2] * bf[8 * q + 2];
      d3 += (float)gv[3] * bf[8 * q + 3];
      d0 += (float)gv[4] * bf[8 * q + 4];
      d1 += (float)gv[5] * bf[8 * q + 5];
      d2 += (float)gv[6] * bf[8 * q + 6];
      d3 += (float)gv[7] * bf[8 * q + 7];
    }
    float gii = (float)sGh[i * 64 + i];
    float val = p[i] - ((d0 + d1) + (d2 + d3)) + gii * bf[i];
    bf[i] = (val > 0.0f) ? 1.0f : -1.0f;
  }
  u64 nm = 0;
#pragma unroll
  for (int k = 0; k < 64; ++k)
    if (bf[k] > 0.0f) nm |= 1ull << k;
  if (!act) nm = 0;
  if (act) Bmask[j] = nm;
  u64 tb = transpose64(nm, lane);
  Brow[(size_t)lane * WPR + g] = tb;
}

// L1: likelihood sum; u staged in LDS as fp16 (broadcast), uc fp32 regs.
__global__ __launch_bounds__(256, 2) void l1_like(
    const float* __restrict__ U, const float* __restrict__ u,
    const signed char* __restrict__ owner, const u64* __restrict__ Ymask,
    const u64* __restrict__ ybatch, double* __restrict__ acc) {
  __shared__ _Float16 shu[8192];
  __shared__ u64 sy[256];
  for (int t = threadIdx.x; t < 8192; t += 256) shu[t] = (_Float16)u[t];
  if (threadIdx.x < 256) sy[threadIdx.x] = ybatch[threadIdx.x];
  __syncthreads();
  int g = blockIdx.x * 4 + (threadIdx.x >> 6);
  int lane = threadIdx.x & 63;
  double lsum = 0.0;
  if (g < 1563) {
    int j = g * 64 + lane;
    if (j < NT) {
      float uc[64];
      int ow = owner[j];
      if (ow >= 0) {
#pragma unroll
        for (int i = 0; i < 64; ++i) uc[i] = u[ow * 64 + i];
      } else {
#pragma unroll
        for (int i = 0; i < 64; ++i) uc[i] = U[(size_t)i * NT + j];
      }
      u64 y0 = Ymask[2 * j], y1 = Ymask[2 * j + 1];
      for (int b = 0; b < 128; ++b) {
        const half8* ub = (const half8*)&shu[b * 64];
        float d0 = 0.f, d1 = 0.f, d2 = 0.f, d3 = 0.f;
#pragma unroll
        for (int q = 0; q < 8; ++q) {
          half8 uv = ub[q];
          d0 += (float)uv[0] * uc[8 * q + 0];
          d1 += (float)uv[1] * uc[8 * q + 1];
          d2 += (float)uv[2] * uc[8 * q + 2];
          d3 += (float)uv[3] * uc[8 * q + 3];
          d0 += (float)uv[4] * uc[8 * q + 4];
          d1 += (float)uv[5] * uc[8 * q + 5];
          d2 += (float)uv[6] * uc[8 * q + 6];
          d3 += (float)uv[7] * uc[8 * q + 7];
        }
        float ip = 0.5f * ((d0 + d1) + (d2 + d3));
        bool s = ((sy[2 * b] & y0) | (sy[2 * b + 1] & y1)) != 0ull;
        float a = fabsf(ip);
        float like = __logf(1.0f + __expf(-a)) + fmaxf(ip, 0.0f) - (s ? ip : 0.0f);
        lsum += (double)like;
      }
    }
  }
  lsum = wave_reduce_f64(lsum);
  if (lane == 0) atomicAdd(&acc[0], lsum);
}

// L2 + finalize
__global__ __launch_bounds__(256) void l2_fin(
    const float* __restrict__ Wr, const float* __restrict__ y,
    const int* __restrict__ ind, const u64* __restrict__ Bmask,
    const double* __restrict__ acc, float* __restrict__ out) {
  __shared__ float sw[6400];
  __shared__ u64 sbm[128];
  __shared__ double dred[8];
  int tid = threadIdx.x;
  for (int t = tid; t < 6400; t += 256) sw[t] = Wr[t];
  if (tid < 128) sbm[tid] = Bmask[ind[tid]];
  __syncthreads();
  double cls = 0.0, regs = 0.0;
  for (int e = tid; e < 12800; e += 256) {
    int c = e >> 7, b = e & 127;
    u64 bm = sbm[b];
    float s = 0.0f;
#pragma unroll
    for (int i = 0; i < 64; ++i) {
      float w = sw[i * 100 + c];
      s += ((bm >> i) & 1ull) ? w : -w;
    }
    float d = y[b * 100 + c] - s;
    cls += (double)(d * d);
  }
  for (int e = tid; e < 6400; e += 256) {
    float w = sw[e];
    regs += (double)(w * w);
  }
  cls = wave_reduce_f64(cls);
  regs = wave_reduce_f64(regs);
  int wv = tid >> 6;
  if ((tid & 63) == 0) { dred[wv] = cls; dred[4 + wv] = regs; }
  __syncthreads();
  if (tid == 0) {
    double c = dred[0] + dred[1] + dred[2] + dred[3];
    double r = dred[4] + dred[5] + dred[6] + dred[7];
    out[0] = (float)(acc[0] * (1.0 / 12800000.0) + c * (1.0 / 12800.0) +
                     r * (0.1 / 6400.0));
  }
}

extern "C" void kernel_launch(void* const* d_in, const int* in_sizes, int n_in,
                              void* d_out, int out_size, void* d_ws, size_t ws_size,
                              hipStream_t stream) {
  const float* u    = (const float*)d_in[0];
  const float* y    = (const float*)d_in[1];
  const int*   ind  = (const int*)d_in[2];
  const float* U    = (const float*)d_in[3];
  const float* B    = (const float*)d_in[4];
  const float* Ybuf = (const float*)d_in[5];
  char* ws = (char*)d_ws;
  double* acc        = (double*)(ws + 0);
  u64* Bmask         = (u64*)(ws + 256);
  u64* Ymask         = (u64*)(ws + 800256);
  u64* Brow          = (u64*)(ws + 2400256);
  u64* Yrow          = (u64*)(ws + 3203072);
  u64* ybatch        = (u64*)(ws + 4457472);
  int* popcY         = (int*)(ws + 4459520);
  int* S_part        = (int*)(ws + 4460032);   // 8*4096 ints
  int* R_part        = (int*)(ws + 4591104);   // 8*6400 ints
  float* Wr          = (float*)(ws + 4795904);
  float* Wc          = (float*)(ws + 4821504);
  float* G           = (float*)(ws + 4847104);
  signed char* owner = (signed char*)(ws + 4863488);

  build_colmasks<<<(NT + 255) / 256, 256, 0, stream>>>(B, Ybuf, Bmask, Ymask, owner);
  scatter_y<<<1, 128, 0, stream>>>(y, ind, Ymask, ybatch, owner, acc);
  build_rows<<<392, 256, 0, stream>>>(Bmask, Ymask, Brow, Yrow);
  popcY_k<<<100, 256, 0, stream>>>(Yrow, popcY);
  for (int it = 0; it < 10; ++it) {
    k1_sr<<<dim3(64, 8), 256, 0, stream>>>(Brow, Yrow, S_part, R_part);
    k2a_solve<<<4, 256, 0, stream>>>(S_part, R_part, popcY, Wr, Wc);
    k2b_gram<<<4, 256, 0, stream>>>(Wr, G);
    k3_gs<<<392, 256, 0, stream>>>(U, u, owner, Wc, G, Bmask, Brow, Ymask);
  }
  l1_like<<<391, 256, 0, stream>>>(U, u, owner, Ymask, ybatch, acc);
  l2_fin<<<1, 256, 0, stream>>>(Wr, y, ind, Bmask, acc, (float*)d_out);
}

// Round 7
// 1085.638 us; speedup vs baseline: 2.2394x; 1.4016x over previous
//
#include <hip/hip_runtime.h>
#include <cstdint>
#include <cstddef>

// DSDHLoss: faithful DCC loop on bitmask representation.
// B (+-1) -> 64-bit column masks + row-major bit-planes; Ybuf (0/1) -> masks.
// S=B B^T and R=B Y^T via popcount (exact integers == fp32 reference values).
// Margins: GS decides sign(55*U + O(1e-2)) -> fp16 in all correction terms
// is far below decision margins.
// k1: padded bit-rows, compile-time chunks, register popcounts.
// k2a: Neumann solve (4 iters), fp16 X broadcasts, W written from registers.
// k2b: G = W W^T.
// k3: fp16 stride-72 W gathers + packed-fp16 P accum + packed-fp16 GS dot.
// l1: 2 cols/thread, packed-fp16 dot, u broadcast from LDS fp16.

#define NT 100000
#define WPR 1568      // padded u64 words per bit-row (1563 real + 5 zero)
#define NWREAL 1563
#define NGRPP 1568    // padded group count
#define ETA_MU 55.0f
#define LAM 0.1f

typedef unsigned long long u64;
typedef _Float16 half8 __attribute__((ext_vector_type(8)));
typedef _Float16 half4 __attribute__((ext_vector_type(4)));
typedef _Float16 half2v __attribute__((ext_vector_type(2)));

__device__ inline float hsum8(half8 a) {
  half4 lo = __builtin_shufflevector(a, a, 0, 1, 2, 3);
  half4 hi = __builtin_shufflevector(a, a, 4, 5, 6, 7);
  half4 s4 = lo + hi;
  half2v l2 = __builtin_shufflevector(s4, s4, 0, 1);
  half2v h2 = __builtin_shufflevector(s4, s4, 2, 3);
  half2v s2 = l2 + h2;
  return (float)s2[0] + (float)s2[1];
}

__device__ inline u64 transpose64(u64 x, int lane) {
  const u64 ms[6] = {0x5555555555555555ull,0x3333333333333333ull,0x0F0F0F0F0F0F0F0Full,
                     0x00FF00FF00FF00FFull,0x0000FFFF0000FFFFull,0x00000000FFFFFFFFull};
#pragma unroll
  for (int si = 0; si < 6; ++si) {
    int s = 1 << si;
    u64 m = ms[si];
    u64 y = __shfl_xor(x, s, 64);
    if ((lane & s) == 0) x = (x & m) | ((y & m) << s);
    else                 x = (x & ~m) | ((y & ~m) >> s);
  }
  return x;
}

__device__ inline int wave_reduce_i32(int v) {
#pragma unroll
  for (int off = 32; off > 0; off >>= 1) v += __shfl_down(v, off, 64);
  return v;
}
__device__ inline double wave_reduce_f64(double v) {
#pragma unroll
  for (int off = 32; off > 0; off >>= 1) v += __shfl_down(v, off, 64);
  return v;
}

// column masks for B and Ybuf, 4 columns per thread (float4 loads)
__global__ __launch_bounds__(256) void build_colmasks(
    const float* __restrict__ B, const float* __restrict__ Ybuf,
    u64* __restrict__ Bmask, u64* __restrict__ Ymask,
    signed char* __restrict__ owner) {
  int j0 = (blockIdx.x * 256 + threadIdx.x) * 4;
  if (j0 >= NT) return;
  *(int*)&owner[j0] = -1;   // four -1 bytes
  u64 bm[4] = {0, 0, 0, 0};
#pragma unroll
  for (int i = 0; i < 64; ++i) {
    float4 v = *(const float4*)&B[(size_t)i * NT + j0];
    bm[0] |= ((u64)(v.x > 0.0f)) << i;
    bm[1] |= ((u64)(v.y > 0.0f)) << i;
    bm[2] |= ((u64)(v.z > 0.0f)) << i;
    bm[3] |= ((u64)(v.w > 0.0f)) << i;
  }
  u64 m0[4] = {0, 0, 0, 0}, m1[4] = {0, 0, 0, 0};
#pragma unroll
  for (int c = 0; c < 100; ++c) {
    float4 v = *(const float4*)&Ybuf[(size_t)c * NT + j0];
    if (c < 64) {
      m0[0] |= ((u64)(v.x > 0.5f)) << c;
      m0[1] |= ((u64)(v.y > 0.5f)) << c;
      m0[2] |= ((u64)(v.z > 0.5f)) << c;
      m0[3] |= ((u64)(v.w > 0.5f)) << c;
    } else {
      m1[0] |= ((u64)(v.x > 0.5f)) << (c - 64);
      m1[1] |= ((u64)(v.y > 0.5f)) << (c - 64);
      m1[2] |= ((u64)(v.z > 0.5f)) << (c - 64);
      m1[3] |= ((u64)(v.w > 0.5f)) << (c - 64);
    }
  }
#pragma unroll
  for (int t = 0; t < 4; ++t) {
    Bmask[j0 + t] = bm[t];
    Ymask[2 * (j0 + t)] = m0[t];
    Ymask[2 * (j0 + t) + 1] = m1[t];
  }
}

// scatter: Ybuf[:, ind[b]] = y[b]; owner[ind[b]] = b; batch y-masks; acc=0
__global__ void scatter_y(const float* __restrict__ y, const int* __restrict__ ind,
                          u64* __restrict__ Ymask, u64* __restrict__ ybatch,
                          signed char* __restrict__ owner, double* __restrict__ acc) {
  int b = threadIdx.x;
  if (b < 4) acc[b] = 0.0;
  if (b >= 128) return;
  u64 m0 = 0, m1 = 0;
  for (int c = 0; c < 100; ++c) {
    bool v = y[b * 100 + c] > 0.5f;
    if (c < 64) m0 |= ((u64)v) << c;
    else        m1 |= ((u64)v) << (c - 64);
  }
  ybatch[2 * b] = m0;
  ybatch[2 * b + 1] = m1;
  int col = ind[b];
  Ymask[2 * col] = m0;
  Ymask[2 * col + 1] = m1;
  owner[col] = (signed char)b;
}

// column masks -> row-major bit planes; groups [1563,1568) write zeros (pad)
__global__ __launch_bounds__(256) void build_rows(
    const u64* __restrict__ Bmask, const u64* __restrict__ Ymask,
    u64* __restrict__ Brow, u64* __restrict__ Yrow) {
  int g = blockIdx.x * 4 + (threadIdx.x >> 6);
  int lane = threadIdx.x & 63;
  if (g >= NGRPP) return;
  int j = g * 64 + lane;
  bool act = j < NT;
  u64 bm = act ? Bmask[j] : 0ull;
  u64 y0 = act ? Ymask[2 * j] : 0ull;
  u64 y1 = act ? Ymask[2 * j + 1] : 0ull;
  u64 tb = transpose64(bm, lane);
  Brow[(size_t)lane * WPR + g] = tb;
  u64 t0 = transpose64(y0, lane);
  Yrow[(size_t)lane * WPR + g] = t0;
  u64 t1 = transpose64(y1, lane);
  if (lane < 36) Yrow[(size_t)(64 + lane) * WPR + g] = t1;
}

// popcY: one block per class
__global__ __launch_bounds__(256) void popcY_k(const u64* __restrict__ Yrow,
                                               int* __restrict__ popcY) {
  int c = blockIdx.x;
  __shared__ int red[4];
  int s = 0;
  for (int w = threadIdx.x; w < NWREAL; w += 256)
    s += __popcll(Yrow[(size_t)c * WPR + w]);
  s = wave_reduce_i32(s);
  if ((threadIdx.x & 63) == 0) red[threadIdx.x >> 6] = s;
  __syncthreads();
  if (threadIdx.x == 0) popcY[c] = red[0] + red[1] + red[2] + red[3];
}

// K1: grid (64 k, 8 q). Chunk = 196 words (compile-time). Register popcounts.
__global__ __launch_bounds__(256, 4) void k1_sr(
    const u64* __restrict__ Brow, const u64* __restrict__ Yrow,
    int* __restrict__ S_part, int* __restrict__ R_part) {
  int k = blockIdx.x;
  int q = blockIdx.y;
  int w0 = q * 196;
  int wv = threadIdx.x >> 6, lane = threadIdx.x & 63;
  u64 tmask = (lane < 4) ? ~0ull : 0ull;
  const u64* bk = Brow + (size_t)k * WPR + w0;
  u64 b0 = bk[lane], b1 = bk[lane + 64], b2 = bk[lane + 128];
  u64 b3 = bk[192 + (lane & 3)] & tmask;
  int sS[16];
#pragma unroll
  for (int m = 0; m < 16; ++m) {
    const u64* br = Brow + (size_t)(4 * m + wv) * WPR + w0;
    u64 x0 = br[lane], x1 = br[lane + 64], x2 = br[lane + 128];
    u64 x3 = br[192 + (lane & 3)] & tmask;
    sS[m] = __popcll(x0 ^ b0) + __popcll(x1 ^ b1) +
            __popcll(x2 ^ b2) + __popcll(x3 ^ b3);
  }
  int sR[25];
#pragma unroll
  for (int m = 0; m < 25; ++m) {
    const u64* yr = Yrow + (size_t)(4 * m + wv) * WPR + w0;
    u64 x0 = yr[lane], x1 = yr[lane + 64], x2 = yr[lane + 128];
    u64 x3 = yr[192 + (lane & 3)] & tmask;
    sR[m] = __popcll(x0 & b0) + __popcll(x1 & b1) +
            __popcll(x2 & b2) + __popcll(x3 & b3);
  }
#pragma unroll
  for (int off = 32; off > 0; off >>= 1) {
#pragma unroll
    for (int m = 0; m < 16; ++m) sS[m] += __shfl_down(sS[m], off, 64);
#pragma unroll
    for (int m = 0; m < 25; ++m) sR[m] += __shfl_down(sR[m], off, 64);
  }
  if (lane == 0) {
#pragma unroll
    for (int m = 0; m < 16; ++m)
      S_part[q * 4096 + k * 64 + 4 * m + wv] = sS[m];
#pragma unroll
    for (int m = 0; m < 25; ++m)
      R_part[q * 6400 + k * 100 + 4 * m + wv] = sR[m];
  }
}

// K2a: Neumann solve X = A^-1 R, columns split across 4 blocks.
// X iterate in fp16 LDS (broadcast); R + final X in fp32 registers.
__global__ __launch_bounds__(256, 1) void k2a_solve(
    const int* __restrict__ S_part, const int* __restrict__ R_part,
    const int* __restrict__ popcY, float* __restrict__ Wr,
    float* __restrict__ Wc) {
  __shared__ short sEi[4096];        // [k][l ^ (k&31)] exact i16
  __shared__ _Float16 sXa[64 * 32];  // [k][local col] fp16, stride 32 halves
  __shared__ _Float16 sXb[64 * 32];
  int tid = threadIdx.x;
  int wv = tid >> 6, k = tid & 63;
  int b = blockIdx.x;
  const int qbase_t[4] = {0, 7, 14, 20};
  const int qcnt_t[4]  = {7, 7, 6, 6};
  int qbase = qbase_t[b], Q = qcnt_t[b];
  const int off7[4] = {0, 2, 4, 6}, cnt7[4] = {2, 2, 2, 1};
  const int off6[4] = {0, 2, 4, 5}, cnt6[4] = {2, 2, 1, 1};
  int woff = (Q == 7) ? off7[wv] : off6[wv];
  int wcnt = (Q == 7) ? cnt7[wv] : cnt6[wv];
  const float alpha = 1.0f / (100000.0f + LAM);
  for (int e = tid; e < 4096; e += 256) {
    int kk = e >> 6, ll = e & 63;
    int mm = 0;
#pragma unroll
    for (int qq = 0; qq < 8; ++qq) mm += S_part[qq * 4096 + e];
    int v = (kk == ll) ? 0 : (NT - 2 * mm);
    v = v > 32767 ? 32767 : (v < -32767 ? -32767 : v);
    sEi[kk * 64 + (ll ^ (kk & 31))] = (short)v;
  }
  float4 rr4[2], xf[2];
#pragma unroll
  for (int q = 0; q < 2; ++q) {
    if (q < wcnt) {
      float tmp[4];
#pragma unroll
      for (int e4 = 0; e4 < 4; ++e4) {
        int cg = 4 * (qbase + woff + q) + e4;
        float rv = 0.0f;
        if (cg < 100) {
          int rr = 0;
#pragma unroll
          for (int qq = 0; qq < 8; ++qq) rr += R_part[qq * 6400 + k * 100 + cg];
          rv = (float)(2 * rr - popcY[cg]);
        }
        tmp[e4] = rv;
      }
      rr4[q] = make_float4(tmp[0], tmp[1], tmp[2], tmp[3]);
      xf[q] = make_float4(alpha * tmp[0], alpha * tmp[1],
                          alpha * tmp[2], alpha * tmp[3]);
    }
  }
  // write X0 fp16
  if (wcnt == 2) {
    half8 h;
    h[0] = (_Float16)xf[0].x; h[1] = (_Float16)xf[0].y;
    h[2] = (_Float16)xf[0].z; h[3] = (_Float16)xf[0].w;
    h[4] = (_Float16)xf[1].x; h[5] = (_Float16)xf[1].y;
    h[6] = (_Float16)xf[1].z; h[7] = (_Float16)xf[1].w;
    *(half8*)&sXa[k * 32 + 4 * woff] = h;
  } else {
    half4 h;
    h[0] = (_Float16)xf[0].x; h[1] = (_Float16)xf[0].y;
    h[2] = (_Float16)xf[0].z; h[3] = (_Float16)xf[0].w;
    *(half4*)&sXa[k * 32 + 4 * woff] = h;
  }
  __syncthreads();
  _Float16* Xs = sXa;
  _Float16* Xd = sXb;
  for (int it = 0; it < 4; ++it) {
    float4 a4[2];
#pragma unroll
    for (int q = 0; q < 2; ++q)
      if (q < wcnt) a4[q] = rr4[q];
    if (wcnt == 2) {
      for (int l = 0; l < 64; ++l) {
        float ev = (float)sEi[k * 64 + (l ^ (k & 31))];
        half8 x8 = *(const half8*)&Xs[l * 32 + 4 * woff];
        a4[0].x -= ev * (float)x8[0]; a4[0].y -= ev * (float)x8[1];
        a4[0].z -= ev * (float)x8[2]; a4[0].w -= ev * (float)x8[3];
        a4[1].x -= ev * (float)x8[4]; a4[1].y -= ev * (float)x8[5];
        a4[1].z -= ev * (float)x8[6]; a4[1].w -= ev * (float)x8[7];
      }
    } else {
      for (int l = 0; l < 64; ++l) {
        float ev = (float)sEi[k * 64 + (l ^ (k & 31))];
        half4 x4 = *(const half4*)&Xs[l * 32 + 4 * woff];
        a4[0].x -= ev * (float)x4[0]; a4[0].y -= ev * (float)x4[1];
        a4[0].z -= ev * (float)x4[2]; a4[0].w -= ev * (float)x4[3];
      }
    }
#pragma unroll
    for (int q = 0; q < 2; ++q) {
      if (q < wcnt) {
        xf[q] = make_float4(alpha * a4[q].x, alpha * a4[q].y,
                            alpha * a4[q].z, alpha * a4[q].w);
      }
    }
    if (it < 3) {
      if (wcnt == 2) {
        half8 h;
        h[0] = (_Float16)xf[0].x; h[1] = (_Float16)xf[0].y;
        h[2] = (_Float16)xf[0].z; h[3] = (_Float16)xf[0].w;
        h[4] = (_Float16)xf[1].x; h[5] = (_Float16)xf[1].y;
        h[6] = (_Float16)xf[1].z; h[7] = (_Float16)xf[1].w;
        *(half8*)&Xd[k * 32 + 4 * woff] = h;
      } else {
        half4 h;
        h[0] = (_Float16)xf[0].x; h[1] = (_Float16)xf[0].y;
        h[2] = (_Float16)xf[0].z; h[3] = (_Float16)xf[0].w;
        *(half4*)&Xd[k * 32 + 4 * woff] = h;
      }
      __syncthreads();
      _Float16* t = Xs; Xs = Xd; Xd = t;
    }
  }
  // final X from fp32 registers
#pragma unroll
  for (int q = 0; q < 2; ++q) {
    if (q < wcnt) {
      float v4[4] = {xf[q].x, xf[q].y, xf[q].z, xf[q].w};
#pragma unroll
      for (int e4 = 0; e4 < 4; ++e4) {
        int cg = 4 * (qbase + woff + q) + e4;
        if (cg < 100) {
          Wr[k * 100 + cg] = v4[e4];
          Wc[cg * 64 + k] = v4[e4];
        }
      }
    }
  }
}

// K2b: G = W W^T, 4 blocks x 16 rows each.
__global__ __launch_bounds__(256, 1) void k2b_gram(
    const float* __restrict__ Wr, float* __restrict__ G) {
  __shared__ float sX[6400];
  int tid = threadIdx.x, wv = tid >> 6, k = tid & 63;
  for (int t = tid; t < 6400; t += 256) sX[t] = Wr[t];
  __syncthreads();
  float4 xl[25];
#pragma unroll
  for (int q = 0; q < 25; ++q) xl[q] = *(const float4*)&sX[k * 100 + 4 * q];
#pragma unroll
  for (int ii = 0; ii < 4; ++ii) {
    int i = blockIdx.x * 16 + wv * 4 + ii;
    const float4* xi = (const float4*)&sX[i * 100];
    float d0 = 0.f, d1 = 0.f, d2 = 0.f, d3 = 0.f;
#pragma unroll
    for (int q = 0; q < 25; ++q) {
      float4 a = xi[q];
      d0 += xl[q].x * a.x; d1 += xl[q].y * a.y;
      d2 += xl[q].z * a.z; d3 += xl[q].w * a.w;
    }
    G[i * 64 + k] = (d0 + d1) + (d2 + d3);
  }
}

// K3: P = W@Ybuf_col (sparse, packed-fp16 accum) + 55*U_col, then exact
// sequential GS sign sweep with packed-fp16 G dot (bf as +-1 fp16).
__global__ __launch_bounds__(256, 2) void k3_gs(
    const float* __restrict__ U, const float* __restrict__ u,
    const signed char* __restrict__ owner, const float* __restrict__ Wc,
    const float* __restrict__ Gm, u64* __restrict__ Bmask,
    u64* __restrict__ Brow, const u64* __restrict__ Ymask) {
  __shared__ _Float16 sWh[100 * 72];   // [c][i], stride 72 halves (144 B, 16B-aligned)
  __shared__ _Float16 sGh[64 * 64];    // [i][k] fp16 (broadcast rows)
  __shared__ float sGd[64];            // diag fp32
  for (int t = threadIdx.x; t < 6400; t += 256) {
    int c = t >> 6, i = t & 63;
    sWh[c * 72 + i] = (_Float16)Wc[t];
  }
  for (int t = threadIdx.x; t < 4096; t += 256) sGh[t] = (_Float16)Gm[t];
  if (threadIdx.x < 64) sGd[threadIdx.x] = Gm[threadIdx.x * 65];
  __syncthreads();
  int g = blockIdx.x * 4 + (threadIdx.x >> 6);   // grid 392 -> g < 1568
  int lane = threadIdx.x & 63;
  int j = g * 64 + lane;
  bool act = j < NT;
  int jc = act ? j : NT - 1;
  int ow = owner[jc];
  float p[64];
  if (ow >= 0) {
#pragma unroll
    for (int i = 0; i < 64; ++i) p[i] = ETA_MU * u[ow * 64 + i];
  } else {
#pragma unroll
    for (int i = 0; i < 64; ++i) p[i] = ETA_MU * U[(size_t)i * NT + jc];
  }
  u64 y0 = Ymask[2 * jc], y1 = Ymask[2 * jc + 1];
  // sparse W-accumulate in packed fp16 (values ~1e-3, sums ~1e-2: safe)
  half8 pw[8];
#pragma unroll
  for (int t = 0; t < 8; ++t) pw[t] = (half8)(_Float16)0.0f;
  u64 mm = y0;
  while (mm) {
    int c = __builtin_ctzll(mm); mm &= mm - 1;
    const half8* wr = (const half8*)&sWh[c * 72];
#pragma unroll
    for (int t = 0; t < 8; ++t) pw[t] += wr[t];
  }
  mm = y1;
  while (mm) {
    int c = 64 + __builtin_ctzll(mm); mm &= mm - 1;
    const half8* wr = (const half8*)&sWh[c * 72];
#pragma unroll
    for (int t = 0; t < 8; ++t) pw[t] += wr[t];
  }
#pragma unroll
  for (int t = 0; t < 8; ++t)
#pragma unroll
    for (int e = 0; e < 8; ++e)
      p[8 * t + e] += (float)pw[t][e];
  // GS sweep: bf as +-1 fp16 vectors
  u64 bm = Bmask[jc];
  half8 bfh[8];
#pragma unroll
  for (int t = 0; t < 8; ++t)
#pragma unroll
    for (int e = 0; e < 8; ++e)
      bfh[t][e] = ((bm >> (8 * t + e)) & 1ull) ? (_Float16)1.0f : (_Float16)-1.0f;
#pragma unroll
  for (int i = 0; i < 64; ++i) {
    const half8* gr = (const half8*)&sGh[i * 64];   // uniform broadcast
    half8 d = gr[0] * bfh[0];
#pragma unroll
    for (int t = 1; t < 8; ++t) d += gr[t] * bfh[t];
    float dot = hsum8(d);
    float bfi = (float)bfh[i >> 3][i & 7];
    float val = p[i] - dot + sGd[i] * bfi;
    bfh[i >> 3][i & 7] = (val > 0.0f) ? (_Float16)1.0f : (_Float16)-1.0f;
  }
  u64 nm = 0;
#pragma unroll
  for (int t = 0; t < 8; ++t)
#pragma unroll
    for (int e = 0; e < 8; ++e)
      if (bfh[t][e] > (_Float16)0.0f) nm |= 1ull << (8 * t + e);
  if (!act) nm = 0;
  if (act) Bmask[j] = nm;
  u64 tb = transpose64(nm, lane);
  Brow[(size_t)lane * WPR + g] = tb;
}

// L1: likelihood sum; 2 columns/thread, packed-fp16 dot, u fp16 in LDS.
__global__ __launch_bounds__(128, 2) void l1_like(
    const float* __restrict__ U, const float* __restrict__ u,
    const signed char* __restrict__ owner, const u64* __restrict__ Ymask,
    const u64* __restrict__ ybatch, double* __restrict__ acc) {
  __shared__ _Float16 shu[8192];
  __shared__ u64 sy[256];
  int tid = threadIdx.x;
  for (int t = tid; t < 8192; t += 128) shu[t] = (_Float16)u[t];
  for (int t = tid; t < 256; t += 128) sy[t] = ybatch[t];
  __syncthreads();
  int j1 = blockIdx.x * 256 + tid;
  int j2 = j1 + 128;
  bool a1 = j1 < NT, a2 = j2 < NT;
  int jc1 = a1 ? j1 : NT - 1;
  int jc2 = a2 ? j2 : NT - 1;
  half8 uc1[8], uc2[8];
  {
    int ow = owner[jc1];
    if (ow >= 0) {
#pragma unroll
      for (int t = 0; t < 8; ++t)
#pragma unroll
        for (int e = 0; e < 8; ++e)
          uc1[t][e] = (_Float16)u[ow * 64 + 8 * t + e];
    } else {
#pragma unroll
      for (int t = 0; t < 8; ++t)
#pragma unroll
        for (int e = 0; e < 8; ++e)
          uc1[t][e] = (_Float16)U[(size_t)(8 * t + e) * NT + jc1];
    }
  }
  {
    int ow = owner[jc2];
    if (ow >= 0) {
#pragma unroll
      for (int t = 0; t < 8; ++t)
#pragma unroll
        for (int e = 0; e < 8; ++e)
          uc2[t][e] = (_Float16)u[ow * 64 + 8 * t + e];
    } else {
#pragma unroll
      for (int t = 0; t < 8; ++t)
#pragma unroll
        for (int e = 0; e < 8; ++e)
          uc2[t][e] = (_Float16)U[(size_t)(8 * t + e) * NT + jc2];
    }
  }
  u64 y01 = Ymask[2 * jc1], y11 = Ymask[2 * jc1 + 1];
  u64 y02 = Ymask[2 * jc2], y12 = Ymask[2 * jc2 + 1];
  double lsum = 0.0;
  for (int b = 0; b < 128; ++b) {
    const half8* ub = (const half8*)&shu[b * 64];
    half8 d1 = ub[0] * uc1[0];
    half8 d2 = ub[0] * uc2[0];
#pragma unroll
    for (int t = 1; t < 8; ++t) {
      half8 uv = ub[t];
      d1 += uv * uc1[t];
      d2 += uv * uc2[t];
    }
    u64 yb0 = sy[2 * b], yb1 = sy[2 * b + 1];
    if (a1) {
      float ip = 0.5f * hsum8(d1);
      bool s = ((yb0 & y01) | (yb1 & y11)) != 0ull;
      float a = fabsf(ip);
      lsum += (double)(__logf(1.0f + __expf(-a)) + fmaxf(ip, 0.0f) - (s ? ip : 0.0f));
    }
    if (a2) {
      float ip = 0.5f * hsum8(d2);
      bool s = ((yb0 & y02) | (yb1 & y12)) != 0ull;
      float a = fabsf(ip);
      lsum += (double)(__logf(1.0f + __expf(-a)) + fmaxf(ip, 0.0f) - (s ? ip : 0.0f));
    }
  }
  lsum = wave_reduce_f64(lsum);
  if ((tid & 63) == 0) atomicAdd(&acc[0], lsum);
}

// L2 + finalize
__global__ __launch_bounds__(256) void l2_fin(
    const float* __restrict__ Wr, const float* __restrict__ y,
    const int* __restrict__ ind, const u64* __restrict__ Bmask,
    const double* __restrict__ acc, float* __restrict__ out) {
  __shared__ float sw[6400];
  __shared__ u64 sbm[128];
  __shared__ double dred[8];
  int tid = threadIdx.x;
  for (int t = tid; t < 6400; t += 256) sw[t] = Wr[t];
  if (tid < 128) sbm[tid] = Bmask[ind[tid]];
  __syncthreads();
  double cls = 0.0, regs = 0.0;
  for (int e = tid; e < 12800; e += 256) {
    int c = e >> 7, b = e & 127;
    u64 bm = sbm[b];
    float s = 0.0f;
#pragma unroll
    for (int i = 0; i < 64; ++i) {
      float w = sw[i * 100 + c];
      s += ((bm >> i) & 1ull) ? w : -w;
    }
    float d = y[b * 100 + c] - s;
    cls += (double)(d * d);
  }
  for (int e = tid; e < 6400; e += 256) {
    float w = sw[e];
    regs += (double)(w * w);
  }
  cls = wave_reduce_f64(cls);
  regs = wave_reduce_f64(regs);
  int wv = tid >> 6;
  if ((tid & 63) == 0) { dred[wv] = cls; dred[4 + wv] = regs; }
  __syncthreads();
  if (tid == 0) {
    double c = dred[0] + dred[1] + dred[2] + dred[3];
    double r = dred[4] + dred[5] + dred[6] + dred[7];
    out[0] = (float)(acc[0] * (1.0 / 12800000.0) + c * (1.0 / 12800.0) +
                     r * (0.1 / 6400.0));
  }
}

extern "C" void kernel_launch(void* const* d_in, const int* in_sizes, int n_in,
                              void* d_out, int out_size, void* d_ws, size_t ws_size,
                              hipStream_t stream) {
  const float* u    = (const float*)d_in[0];
  const float* y    = (const float*)d_in[1];
  const int*   ind  = (const int*)d_in[2];
  const float* U    = (const float*)d_in[3];
  const float* B    = (const float*)d_in[4];
  const float* Ybuf = (const float*)d_in[5];
  char* ws = (char*)d_ws;
  double* acc        = (double*)(ws + 0);
  u64* Bmask         = (u64*)(ws + 256);
  u64* Ymask         = (u64*)(ws + 800256);
  u64* Brow          = (u64*)(ws + 2400256);
  u64* Yrow          = (u64*)(ws + 3203072);
  u64* ybatch        = (u64*)(ws + 4457472);
  int* popcY         = (int*)(ws + 4459520);
  int* S_part        = (int*)(ws + 4460032);   // 8*4096 ints
  int* R_part        = (int*)(ws + 4591104);   // 8*6400 ints
  float* Wr          = (float*)(ws + 4795904);
  float* Wc          = (float*)(ws + 4821504);
  float* G           = (float*)(ws + 4847104);
  signed char* owner = (signed char*)(ws + 4863488);

  build_colmasks<<<98, 256, 0, stream>>>(B, Ybuf, Bmask, Ymask, owner);
  scatter_y<<<1, 128, 0, stream>>>(y, ind, Ymask, ybatch, owner, acc);
  build_rows<<<392, 256, 0, stream>>>(Bmask, Ymask, Brow, Yrow);
  popcY_k<<<100, 256, 0, stream>>>(Yrow, popcY);
  for (int it = 0; it < 10; ++it) {
    k1_sr<<<dim3(64, 8), 256, 0, stream>>>(Brow, Yrow, S_part, R_part);
    k2a_solve<<<4, 256, 0, stream>>>(S_part, R_part, popcY, Wr, Wc);
    k2b_gram<<<4, 256, 0, stream>>>(Wr, G);
    k3_gs<<<392, 256, 0, stream>>>(U, u, owner, Wc, G, Bmask, Brow, Ymask);
  }
  l1_like<<<391, 128, 0, stream>>>(U, u, owner, Ymask, ybatch, acc);
  l2_fin<<<1, 256, 0, stream>>>(Wr, y, ind, Bmask, acc, (float*)d_out);
}

// Round 8
// 1029.765 us; speedup vs baseline: 2.3609x; 1.0543x over previous
//
#include <hip/hip_runtime.h>
#include <cstdint>
#include <cstddef>

// DSDHLoss: faithful DCC loop on bitmask representation.
// B (+-1) -> 64-bit column masks + row-major bit-planes; Ybuf (0/1) -> masks.
// S=B B^T and R=B Y^T via popcount (exact integers == fp32 reference values).
// Margins: GS decides sign(55*U + O(1e-2)) -> fp16 in all correction terms
// is far below decision margins.
// k1: padded bit-rows, compile-time chunks, register popcounts.
// k2a: Neumann solve (4 iters), fp16 X broadcasts, W written from registers.
// k2b: G = W W^T.
// k3: fp16 stride-72 W gathers + packed-fp16 P accum + packed-fp16 GS dot.
// l1: MFMA (16x16x32 f16) GEMM u @ Ucols with softplus epilogue; per-block
//     partial sums (no same-address f64 atomics), reduced in l2_fin.

#define NT 100000
#define WPR 1568      // padded u64 words per bit-row (1563 real + 5 zero)
#define NWREAL 1563
#define NGRPP 1568    // padded group count
#define NJB 1563      // ceil(NT/64) l1 blocks
#define ETA_MU 55.0f
#define LAM 0.1f

typedef unsigned long long u64;
typedef _Float16 half8 __attribute__((ext_vector_type(8)));
typedef _Float16 half4 __attribute__((ext_vector_type(4)));
typedef _Float16 half2v __attribute__((ext_vector_type(2)));
typedef float float4v __attribute__((ext_vector_type(4)));

__device__ inline float hsum8(half8 a) {
  half4 lo = __builtin_shufflevector(a, a, 0, 1, 2, 3);
  half4 hi = __builtin_shufflevector(a, a, 4, 5, 6, 7);
  half4 s4 = lo + hi;
  half2v l2 = __builtin_shufflevector(s4, s4, 0, 1);
  half2v h2 = __builtin_shufflevector(s4, s4, 2, 3);
  half2v s2 = l2 + h2;
  return (float)s2[0] + (float)s2[1];
}

__device__ inline u64 transpose64(u64 x, int lane) {
  const u64 ms[6] = {0x5555555555555555ull,0x3333333333333333ull,0x0F0F0F0F0F0F0F0Full,
                     0x00FF00FF00FF00FFull,0x0000FFFF0000FFFFull,0x00000000FFFFFFFFull};
#pragma unroll
  for (int si = 0; si < 6; ++si) {
    int s = 1 << si;
    u64 m = ms[si];
    u64 y = __shfl_xor(x, s, 64);
    if ((lane & s) == 0) x = (x & m) | ((y & m) << s);
    else                 x = (x & ~m) | ((y & ~m) >> s);
  }
  return x;
}

__device__ inline int wave_reduce_i32(int v) {
#pragma unroll
  for (int off = 32; off > 0; off >>= 1) v += __shfl_down(v, off, 64);
  return v;
}
__device__ inline double wave_reduce_f64(double v) {
#pragma unroll
  for (int off = 32; off > 0; off >>= 1) v += __shfl_down(v, off, 64);
  return v;
}

// column masks for B and Ybuf, 4 columns per thread (float4 loads)
__global__ __launch_bounds__(256) void build_colmasks(
    const float* __restrict__ B, const float* __restrict__ Ybuf,
    u64* __restrict__ Bmask, u64* __restrict__ Ymask,
    signed char* __restrict__ owner) {
  int j0 = (blockIdx.x * 256 + threadIdx.x) * 4;
  if (j0 >= NT) return;
  *(int*)&owner[j0] = -1;   // four -1 bytes
  u64 bm[4] = {0, 0, 0, 0};
#pragma unroll
  for (int i = 0; i < 64; ++i) {
    float4 v = *(const float4*)&B[(size_t)i * NT + j0];
    bm[0] |= ((u64)(v.x > 0.0f)) << i;
    bm[1] |= ((u64)(v.y > 0.0f)) << i;
    bm[2] |= ((u64)(v.z > 0.0f)) << i;
    bm[3] |= ((u64)(v.w > 0.0f)) << i;
  }
  u64 m0[4] = {0, 0, 0, 0}, m1[4] = {0, 0, 0, 0};
#pragma unroll
  for (int c = 0; c < 100; ++c) {
    float4 v = *(const float4*)&Ybuf[(size_t)c * NT + j0];
    if (c < 64) {
      m0[0] |= ((u64)(v.x > 0.5f)) << c;
      m0[1] |= ((u64)(v.y > 0.5f)) << c;
      m0[2] |= ((u64)(v.z > 0.5f)) << c;
      m0[3] |= ((u64)(v.w > 0.5f)) << c;
    } else {
      m1[0] |= ((u64)(v.x > 0.5f)) << (c - 64);
      m1[1] |= ((u64)(v.y > 0.5f)) << (c - 64);
      m1[2] |= ((u64)(v.z > 0.5f)) << (c - 64);
      m1[3] |= ((u64)(v.w > 0.5f)) << (c - 64);
    }
  }
#pragma unroll
  for (int t = 0; t < 4; ++t) {
    Bmask[j0 + t] = bm[t];
    Ymask[2 * (j0 + t)] = m0[t];
    Ymask[2 * (j0 + t) + 1] = m1[t];
  }
}

// scatter: Ybuf[:, ind[b]] = y[b]; owner[ind[b]] = b; batch y-masks
__global__ void scatter_y(const float* __restrict__ y, const int* __restrict__ ind,
                          u64* __restrict__ Ymask, u64* __restrict__ ybatch,
                          signed char* __restrict__ owner) {
  int b = threadIdx.x;
  if (b >= 128) return;
  u64 m0 = 0, m1 = 0;
  for (int c = 0; c < 100; ++c) {
    bool v = y[b * 100 + c] > 0.5f;
    if (c < 64) m0 |= ((u64)v) << c;
    else        m1 |= ((u64)v) << (c - 64);
  }
  ybatch[2 * b] = m0;
  ybatch[2 * b + 1] = m1;
  int col = ind[b];
  Ymask[2 * col] = m0;
  Ymask[2 * col + 1] = m1;
  owner[col] = (signed char)b;
}

// column masks -> row-major bit planes; groups [1563,1568) write zeros (pad)
__global__ __launch_bounds__(256) void build_rows(
    const u64* __restrict__ Bmask, const u64* __restrict__ Ymask,
    u64* __restrict__ Brow, u64* __restrict__ Yrow) {
  int g = blockIdx.x * 4 + (threadIdx.x >> 6);
  int lane = threadIdx.x & 63;
  if (g >= NGRPP) return;
  int j = g * 64 + lane;
  bool act = j < NT;
  u64 bm = act ? Bmask[j] : 0ull;
  u64 y0 = act ? Ymask[2 * j] : 0ull;
  u64 y1 = act ? Ymask[2 * j + 1] : 0ull;
  u64 tb = transpose64(bm, lane);
  Brow[(size_t)lane * WPR + g] = tb;
  u64 t0 = transpose64(y0, lane);
  Yrow[(size_t)lane * WPR + g] = t0;
  u64 t1 = transpose64(y1, lane);
  if (lane < 36) Yrow[(size_t)(64 + lane) * WPR + g] = t1;
}

// popcY: one block per class
__global__ __launch_bounds__(256) void popcY_k(const u64* __restrict__ Yrow,
                                               int* __restrict__ popcY) {
  int c = blockIdx.x;
  __shared__ int red[4];
  int s = 0;
  for (int w = threadIdx.x; w < NWREAL; w += 256)
    s += __popcll(Yrow[(size_t)c * WPR + w]);
  s = wave_reduce_i32(s);
  if ((threadIdx.x & 63) == 0) red[threadIdx.x >> 6] = s;
  __syncthreads();
  if (threadIdx.x == 0) popcY[c] = red[0] + red[1] + red[2] + red[3];
}

// K1: grid (64 k, 8 q). Chunk = 196 words (compile-time). Register popcounts.
__global__ __launch_bounds__(256, 4) void k1_sr(
    const u64* __restrict__ Brow, const u64* __restrict__ Yrow,
    int* __restrict__ S_part, int* __restrict__ R_part) {
  int k = blockIdx.x;
  int q = blockIdx.y;
  int w0 = q * 196;
  int wv = threadIdx.x >> 6, lane = threadIdx.x & 63;
  u64 tmask = (lane < 4) ? ~0ull : 0ull;
  const u64* bk = Brow + (size_t)k * WPR + w0;
  u64 b0 = bk[lane], b1 = bk[lane + 64], b2 = bk[lane + 128];
  u64 b3 = bk[192 + (lane & 3)] & tmask;
  int sS[16];
#pragma unroll
  for (int m = 0; m < 16; ++m) {
    const u64* br = Brow + (size_t)(4 * m + wv) * WPR + w0;
    u64 x0 = br[lane], x1 = br[lane + 64], x2 = br[lane + 128];
    u64 x3 = br[192 + (lane & 3)] & tmask;
    sS[m] = __popcll(x0 ^ b0) + __popcll(x1 ^ b1) +
            __popcll(x2 ^ b2) + __popcll(x3 ^ b3);
  }
  int sR[25];
#pragma unroll
  for (int m = 0; m < 25; ++m) {
    const u64* yr = Yrow + (size_t)(4 * m + wv) * WPR + w0;
    u64 x0 = yr[lane], x1 = yr[lane + 64], x2 = yr[lane + 128];
    u64 x3 = yr[192 + (lane & 3)] & tmask;
    sR[m] = __popcll(x0 & b0) + __popcll(x1 & b1) +
            __popcll(x2 & b2) + __popcll(x3 & b3);
  }
#pragma unroll
  for (int off = 32; off > 0; off >>= 1) {
#pragma unroll
    for (int m = 0; m < 16; ++m) sS[m] += __shfl_down(sS[m], off, 64);
#pragma unroll
    for (int m = 0; m < 25; ++m) sR[m] += __shfl_down(sR[m], off, 64);
  }
  if (lane == 0) {
#pragma unroll
    for (int m = 0; m < 16; ++m)
      S_part[q * 4096 + k * 64 + 4 * m + wv] = sS[m];
#pragma unroll
    for (int m = 0; m < 25; ++m)
      R_part[q * 6400 + k * 100 + 4 * m + wv] = sR[m];
  }
}

// K2a: Neumann solve X = A^-1 R, columns split across 4 blocks.
// X iterate in fp16 LDS (broadcast); R + final X in fp32 registers.
__global__ __launch_bounds__(256, 1) void k2a_solve(
    const int* __restrict__ S_part, const int* __restrict__ R_part,
    const int* __restrict__ popcY, float* __restrict__ Wr,
    float* __restrict__ Wc) {
  __shared__ short sEi[4096];        // [k][l ^ (k&31)] exact i16
  __shared__ _Float16 sXa[64 * 32];  // [k][local col] fp16, stride 32 halves
  __shared__ _Float16 sXb[64 * 32];
  int tid = threadIdx.x;
  int wv = tid >> 6, k = tid & 63;
  int b = blockIdx.x;
  const int qbase_t[4] = {0, 7, 14, 20};
  const int qcnt_t[4]  = {7, 7, 6, 6};
  int qbase = qbase_t[b], Q = qcnt_t[b];
  const int off7[4] = {0, 2, 4, 6}, cnt7[4] = {2, 2, 2, 1};
  const int off6[4] = {0, 2, 4, 5}, cnt6[4] = {2, 2, 1, 1};
  int woff = (Q == 7) ? off7[wv] : off6[wv];
  int wcnt = (Q == 7) ? cnt7[wv] : cnt6[wv];
  const float alpha = 1.0f / (100000.0f + LAM);
  for (int e = tid; e < 4096; e += 256) {
    int kk = e >> 6, ll = e & 63;
    int mm = 0;
#pragma unroll
    for (int qq = 0; qq < 8; ++qq) mm += S_part[qq * 4096 + e];
    int v = (kk == ll) ? 0 : (NT - 2 * mm);
    v = v > 32767 ? 32767 : (v < -32767 ? -32767 : v);
    sEi[kk * 64 + (ll ^ (kk & 31))] = (short)v;
  }
  float4 rr4[2], xf[2];
#pragma unroll
  for (int q = 0; q < 2; ++q) {
    if (q < wcnt) {
      float tmp[4];
#pragma unroll
      for (int e4 = 0; e4 < 4; ++e4) {
        int cg = 4 * (qbase + woff + q) + e4;
        float rv = 0.0f;
        if (cg < 100) {
          int rr = 0;
#pragma unroll
          for (int qq = 0; qq < 8; ++qq) rr += R_part[qq * 6400 + k * 100 + cg];
          rv = (float)(2 * rr - popcY[cg]);
        }
        tmp[e4] = rv;
      }
      rr4[q] = make_float4(tmp[0], tmp[1], tmp[2], tmp[3]);
      xf[q] = make_float4(alpha * tmp[0], alpha * tmp[1],
                          alpha * tmp[2], alpha * tmp[3]);
    }
  }
  // write X0 fp16
  if (wcnt == 2) {
    half8 h;
    h[0] = (_Float16)xf[0].x; h[1] = (_Float16)xf[0].y;
    h[2] = (_Float16)xf[0].z; h[3] = (_Float16)xf[0].w;
    h[4] = (_Float16)xf[1].x; h[5] = (_Float16)xf[1].y;
    h[6] = (_Float16)xf[1].z; h[7] = (_Float16)xf[1].w;
    *(half8*)&sXa[k * 32 + 4 * woff] = h;
  } else {
    half4 h;
    h[0] = (_Float16)xf[0].x; h[1] = (_Float16)xf[0].y;
    h[2] = (_Float16)xf[0].z; h[3] = (_Float16)xf[0].w;
    *(half4*)&sXa[k * 32 + 4 * woff] = h;
  }
  __syncthreads();
  _Float16* Xs = sXa;
  _Float16* Xd = sXb;
  for (int it = 0; it < 4; ++it) {
    float4 a4[2];
#pragma unroll
    for (int q = 0; q < 2; ++q)
      if (q < wcnt) a4[q] = rr4[q];
    if (wcnt == 2) {
      for (int l = 0; l < 64; ++l) {
        float ev = (float)sEi[k * 64 + (l ^ (k & 31))];
        half8 x8 = *(const half8*)&Xs[l * 32 + 4 * woff];
        a4[0].x -= ev * (float)x8[0]; a4[0].y -= ev * (float)x8[1];
        a4[0].z -= ev * (float)x8[2]; a4[0].w -= ev * (float)x8[3];
        a4[1].x -= ev * (float)x8[4]; a4[1].y -= ev * (float)x8[5];
        a4[1].z -= ev * (float)x8[6]; a4[1].w -= ev * (float)x8[7];
      }
    } else {
      for (int l = 0; l < 64; ++l) {
        float ev = (float)sEi[k * 64 + (l ^ (k & 31))];
        half4 x4 = *(const half4*)&Xs[l * 32 + 4 * woff];
        a4[0].x -= ev * (float)x4[0]; a4[0].y -= ev * (float)x4[1];
        a4[0].z -= ev * (float)x4[2]; a4[0].w -= ev * (float)x4[3];
      }
    }
#pragma unroll
    for (int q = 0; q < 2; ++q) {
      if (q < wcnt) {
        xf[q] = make_float4(alpha * a4[q].x, alpha * a4[q].y,
                            alpha * a4[q].z, alpha * a4[q].w);
      }
    }
    if (it < 3) {
      if (wcnt == 2) {
        half8 h;
        h[0] = (_Float16)xf[0].x; h[1] = (_Float16)xf[0].y;
        h[2] = (_Float16)xf[0].z; h[3] = (_Float16)xf[0].w;
        h[4] = (_Float16)xf[1].x; h[5] = (_Float16)xf[1].y;
        h[6] = (_Float16)xf[1].z; h[7] = (_Float16)xf[1].w;
        *(half8*)&Xd[k * 32 + 4 * woff] = h;
      } else {
        half4 h;
        h[0] = (_Float16)xf[0].x; h[1] = (_Float16)xf[0].y;
        h[2] = (_Float16)xf[0].z; h[3] = (_Float16)xf[0].w;
        *(half4*)&Xd[k * 32 + 4 * woff] = h;
      }
      __syncthreads();
      _Float16* t = Xs; Xs = Xd; Xd = t;
    }
  }
  // final X from fp32 registers
#pragma unroll
  for (int q = 0; q < 2; ++q) {
    if (q < wcnt) {
      float v4[4] = {xf[q].x, xf[q].y, xf[q].z, xf[q].w};
#pragma unroll
      for (int e4 = 0; e4 < 4; ++e4) {
        int cg = 4 * (qbase + woff + q) + e4;
        if (cg < 100) {
          Wr[k * 100 + cg] = v4[e4];
          Wc[cg * 64 + k] = v4[e4];
        }
      }
    }
  }
}

// K2b: G = W W^T, 4 blocks x 16 rows each.
__global__ __launch_bounds__(256, 1) void k2b_gram(
    const float* __restrict__ Wr, float* __restrict__ G) {
  __shared__ float sX[6400];
  int tid = threadIdx.x, wv = tid >> 6, k = tid & 63;
  for (int t = tid; t < 6400; t += 256) sX[t] = Wr[t];
  __syncthreads();
  float4 xl[25];
#pragma unroll
  for (int q = 0; q < 25; ++q) xl[q] = *(const float4*)&sX[k * 100 + 4 * q];
#pragma unroll
  for (int ii = 0; ii < 4; ++ii) {
    int i = blockIdx.x * 16 + wv * 4 + ii;
    const float4* xi = (const float4*)&sX[i * 100];
    float d0 = 0.f, d1 = 0.f, d2 = 0.f, d3 = 0.f;
#pragma unroll
    for (int q = 0; q < 25; ++q) {
      float4 a = xi[q];
      d0 += xl[q].x * a.x; d1 += xl[q].y * a.y;
      d2 += xl[q].z * a.z; d3 += xl[q].w * a.w;
    }
    G[i * 64 + k] = (d0 + d1) + (d2 + d3);
  }
}

// K3: P = W@Ybuf_col (sparse, packed-fp16 accum) + 55*U_col, then exact
// sequential GS sign sweep with packed-fp16 G dot (bf as +-1 fp16).
__global__ __launch_bounds__(256, 2) void k3_gs(
    const float* __restrict__ U, const float* __restrict__ u,
    const signed char* __restrict__ owner, const float* __restrict__ Wc,
    const float* __restrict__ Gm, u64* __restrict__ Bmask,
    u64* __restrict__ Brow, const u64* __restrict__ Ymask) {
  __shared__ _Float16 sWh[100 * 72];   // [c][i], stride 72 halves (144 B, 16B-aligned)
  __shared__ _Float16 sGh[64 * 64];    // [i][k] fp16 (broadcast rows)
  __shared__ float sGd[64];            // diag fp32
  for (int t = threadIdx.x; t < 6400; t += 256) {
    int c = t >> 6, i = t & 63;
    sWh[c * 72 + i] = (_Float16)Wc[t];
  }
  for (int t = threadIdx.x; t < 4096; t += 256) sGh[t] = (_Float16)Gm[t];
  if (threadIdx.x < 64) sGd[threadIdx.x] = Gm[threadIdx.x * 65];
  __syncthreads();
  int g = blockIdx.x * 4 + (threadIdx.x >> 6);   // grid 392 -> g < 1568
  int lane = threadIdx.x & 63;
  int j = g * 64 + lane;
  bool act = j < NT;
  int jc = act ? j : NT - 1;
  int ow = owner[jc];
  float p[64];
  if (ow >= 0) {
#pragma unroll
    for (int i = 0; i < 64; ++i) p[i] = ETA_MU * u[ow * 64 + i];
  } else {
#pragma unroll
    for (int i = 0; i < 64; ++i) p[i] = ETA_MU * U[(size_t)i * NT + jc];
  }
  u64 y0 = Ymask[2 * jc], y1 = Ymask[2 * jc + 1];
  // sparse W-accumulate in packed fp16 (values ~1e-3, sums ~1e-2: safe)
  half8 pw[8];
#pragma unroll
  for (int t = 0; t < 8; ++t) pw[t] = (half8)(_Float16)0.0f;
  u64 mm = y0;
  while (mm) {
    int c = __builtin_ctzll(mm); mm &= mm - 1;
    const half8* wr = (const half8*)&sWh[c * 72];
#pragma unroll
    for (int t = 0; t < 8; ++t) pw[t] += wr[t];
  }
  mm = y1;
  while (mm) {
    int c = 64 + __builtin_ctzll(mm); mm &= mm - 1;
    const half8* wr = (const half8*)&sWh[c * 72];
#pragma unroll
    for (int t = 0; t < 8; ++t) pw[t] += wr[t];
  }
#pragma unroll
  for (int t = 0; t < 8; ++t)
#pragma unroll
    for (int e = 0; e < 8; ++e)
      p[8 * t + e] += (float)pw[t][e];
  // GS sweep: bf as +-1 fp16 vectors
  u64 bm = Bmask[jc];
  half8 bfh[8];
#pragma unroll
  for (int t = 0; t < 8; ++t)
#pragma unroll
    for (int e = 0; e < 8; ++e)
      bfh[t][e] = ((bm >> (8 * t + e)) & 1ull) ? (_Float16)1.0f : (_Float16)-1.0f;
#pragma unroll
  for (int i = 0; i < 64; ++i) {
    const half8* gr = (const half8*)&sGh[i * 64];   // uniform broadcast
    half8 d = gr[0] * bfh[0];
#pragma unroll
    for (int t = 1; t < 8; ++t) d += gr[t] * bfh[t];
    float dot = hsum8(d);
    float bfi = (float)bfh[i >> 3][i & 7];
    float val = p[i] - dot + sGd[i] * bfi;
    bfh[i >> 3][i & 7] = (val > 0.0f) ? (_Float16)1.0f : (_Float16)-1.0f;
  }
  u64 nm = 0;
#pragma unroll
  for (int t = 0; t < 8; ++t)
#pragma unroll
    for (int e = 0; e < 8; ++e)
      if (bfh[t][e] > (_Float16)0.0f) nm |= 1ull << (8 * t + e);
  if (!act) nm = 0;
  if (act) Bmask[j] = nm;
  u64 tb = transpose64(nm, lane);
  Brow[(size_t)lane * WPR + g] = tb;
}

// L1 (MFMA): ip = 0.5 * (u @ Ucols) via mfma_f32_16x16x32_f16.
// Block: 64 cols (4 waves x 16), all 128 batch rows (8 tiles of 16).
// A = u rows from XOR-swizzled fp16 LDS; B = U cols (owner-substituted).
// C/D: col=lane&15 row=quad*4+reg; A: [m=lane&15][k=quad*8+j];
// B: [k=quad*8+j][n=lane&15]. Per-block partial sum -> partial[].
__global__ __launch_bounds__(256, 4) void l1_like(
    const float* __restrict__ U, const float* __restrict__ u,
    const signed char* __restrict__ owner, const u64* __restrict__ Ymask,
    const u64* __restrict__ ybatch, double* __restrict__ partial) {
  __shared__ _Float16 shu[8192];   // u fp16, row b: k8 stored at (k8 ^ (b&7))
  __shared__ u64 sy[256];
  __shared__ double wred[4];
  int tid = threadIdx.x;
  for (int e = tid; e < 1024; e += 256) {
    int b = e >> 3, k8 = e & 7;
    const float4* src = (const float4*)&u[b * 64 + k8 * 8];
    float4 f0 = src[0], f1 = src[1];
    half8 h;
    h[0] = (_Float16)f0.x; h[1] = (_Float16)f0.y;
    h[2] = (_Float16)f0.z; h[3] = (_Float16)f0.w;
    h[4] = (_Float16)f1.x; h[5] = (_Float16)f1.y;
    h[6] = (_Float16)f1.z; h[7] = (_Float16)f1.w;
    *(half8*)&shu[b * 64 + ((k8 ^ (b & 7)) * 8)] = h;
  }
  if (tid < 256) sy[tid] = ybatch[tid];
  __syncthreads();
  int wv = tid >> 6, lane = tid & 63;
  int n = lane & 15, q = lane >> 4;
  int j = blockIdx.x * 64 + wv * 16 + n;
  bool actj = j < NT;
  int jc = actj ? j : NT - 1;
  int ow = owner[jc];
  half8 bf0, bf1;
#pragma unroll
  for (int t = 0; t < 8; ++t) {
    int k = q * 8 + t;
    bf0[t] = (_Float16)U[(size_t)k * NT + jc];
    bf1[t] = (_Float16)U[(size_t)(k + 32) * NT + jc];
  }
  if (ow >= 0) {
#pragma unroll
    for (int t = 0; t < 8; ++t) {
      bf0[t] = (_Float16)u[ow * 64 + q * 8 + t];
      bf1[t] = (_Float16)u[ow * 64 + 32 + q * 8 + t];
    }
  }
  u64 ym0 = Ymask[2 * jc], ym1 = Ymask[2 * jc + 1];
  float lsum = 0.0f;
#pragma unroll
  for (int t8 = 0; t8 < 8; ++t8) {
    int brow = t8 * 16 + n;
    half8 a0 = *(const half8*)&shu[brow * 64 + ((q ^ (brow & 7)) * 8)];
    half8 a1 = *(const half8*)&shu[brow * 64 + (((q + 4) ^ (brow & 7)) * 8)];
    float4v c = {0.f, 0.f, 0.f, 0.f};
    c = __builtin_amdgcn_mfma_f32_16x16x32_f16(a0, bf0, c, 0, 0, 0);
    c = __builtin_amdgcn_mfma_f32_16x16x32_f16(a1, bf1, c, 0, 0, 0);
#pragma unroll
    for (int r = 0; r < 4; ++r) {
      int b = t8 * 16 + q * 4 + r;
      float ip = 0.5f * c[r];
      u64 yb0 = sy[2 * b], yb1 = sy[2 * b + 1];
      bool s = ((yb0 & ym0) | (yb1 & ym1)) != 0ull;
      float a = fabsf(ip);
      lsum += __logf(1.0f + __expf(-a)) + fmaxf(ip, 0.0f) - (s ? ip : 0.0f);
    }
  }
  if (!actj) lsum = 0.0f;
  double lsd = wave_reduce_f64((double)lsum);
  if (lane == 0) wred[wv] = lsd;
  __syncthreads();
  if (tid == 0)
    partial[blockIdx.x] = wred[0] + wred[1] + wred[2] + wred[3];
}

// L2 + finalize: cl_loss + reg_loss + sum of l1 partials.
__global__ __launch_bounds__(256) void l2_fin(
    const float* __restrict__ Wr, const float* __restrict__ y,
    const int* __restrict__ ind, const u64* __restrict__ Bmask,
    const double* __restrict__ partial, float* __restrict__ out) {
  __shared__ float sw[6400];
  __shared__ u64 sbm[128];
  __shared__ double dred[12];
  int tid = threadIdx.x;
  for (int t = tid; t < 6400; t += 256) sw[t] = Wr[t];
  if (tid < 128) sbm[tid] = Bmask[ind[tid]];
  __syncthreads();
  double cls = 0.0, regs = 0.0, l1s = 0.0;
  for (int e = tid; e < 12800; e += 256) {
    int c = e >> 7, b = e & 127;
    u64 bm = sbm[b];
    float s = 0.0f;
#pragma unroll
    for (int i = 0; i < 64; ++i) {
      float w = sw[i * 100 + c];
      s += ((bm >> i) & 1ull) ? w : -w;
    }
    float d = y[b * 100 + c] - s;
    cls += (double)(d * d);
  }
  for (int e = tid; e < 6400; e += 256) {
    float w = sw[e];
    regs += (double)(w * w);
  }
  for (int t = tid; t < NJB; t += 256) l1s += partial[t];
  cls = wave_reduce_f64(cls);
  regs = wave_reduce_f64(regs);
  l1s = wave_reduce_f64(l1s);
  int wv = tid >> 6;
  if ((tid & 63) == 0) { dred[wv] = cls; dred[4 + wv] = regs; dred[8 + wv] = l1s; }
  __syncthreads();
  if (tid == 0) {
    double c = dred[0] + dred[1] + dred[2] + dred[3];
    double r = dred[4] + dred[5] + dred[6] + dred[7];
    double l = dred[8] + dred[9] + dred[10] + dred[11];
    out[0] = (float)(l * (1.0 / 12800000.0) + c * (1.0 / 12800.0) +
                     r * (0.1 / 6400.0));
  }
}

extern "C" void kernel_launch(void* const* d_in, const int* in_sizes, int n_in,
                              void* d_out, int out_size, void* d_ws, size_t ws_size,
                              hipStream_t stream) {
  const float* u    = (const float*)d_in[0];
  const float* y    = (const float*)d_in[1];
  const int*   ind  = (const int*)d_in[2];
  const float* U    = (const float*)d_in[3];
  const float* B    = (const float*)d_in[4];
  const float* Ybuf = (const float*)d_in[5];
  char* ws = (char*)d_ws;
  u64* Bmask         = (u64*)(ws + 256);
  u64* Ymask         = (u64*)(ws + 800256);
  u64* Brow          = (u64*)(ws + 2400256);
  u64* Yrow          = (u64*)(ws + 3203072);
  u64* ybatch        = (u64*)(ws + 4457472);
  int* popcY         = (int*)(ws + 4459520);
  int* S_part        = (int*)(ws + 4460032);   // 8*4096 ints
  int* R_part        = (int*)(ws + 4591104);   // 8*6400 ints
  float* Wr          = (float*)(ws + 4795904);
  float* Wc          = (float*)(ws + 4821504);
  float* G           = (float*)(ws + 4847104);
  signed char* owner = (signed char*)(ws + 4863488);
  double* partial    = (double*)(ws + 4963520); // NJB doubles

  build_colmasks<<<98, 256, 0, stream>>>(B, Ybuf, Bmask, Ymask, owner);
  scatter_y<<<1, 128, 0, stream>>>(y, ind, Ymask, ybatch, owner);
  build_rows<<<392, 256, 0, stream>>>(Bmask, Ymask, Brow, Yrow);
  popcY_k<<<100, 256, 0, stream>>>(Yrow, popcY);
  for (int it = 0; it < 10; ++it) {
    k1_sr<<<dim3(64, 8), 256, 0, stream>>>(Brow, Yrow, S_part, R_part);
    k2a_solve<<<4, 256, 0, stream>>>(S_part, R_part, popcY, Wr, Wc);
    k2b_gram<<<4, 256, 0, stream>>>(Wr, G);
    k3_gs<<<392, 256, 0, stream>>>(U, u, owner, Wc, G, Bmask, Brow, Ymask);
  }
  l1_like<<<NJB, 256, 0, stream>>>(U, u, owner, Ymask, ybatch, partial);
  l2_fin<<<1, 256, 0, stream>>>(Wr, y, ind, Bmask, partial, (float*)d_out);
}